// Round 8
// baseline (2096.880 us; speedup 1.0000x reference)
//
#include <hip/hip_runtime.h>
#include <hip/hip_bf16.h>
#include <math.h>

#define D_MODEL 1024
#define NHEADS  16
#define HDIM    64
#define NEXP    8
#define FFH     2048
#define BATCH   2
#define SEQ     1024
#define NTOK    2048
#define VOCAB   32000
#define LDSS    40   // LDS row stride in shorts (80 B, 16B-aligned, conflict-light)

typedef __attribute__((ext_vector_type(4))) float f32x4;
typedef __attribute__((ext_vector_type(2))) float f32x2;
typedef __attribute__((ext_vector_type(8))) __bf16 bf16x8;
typedef __attribute__((ext_vector_type(4))) unsigned short u16x4;

__device__ __forceinline__ unsigned short f2bf(float f) {
    union { float f; unsigned u; } v; v.f = f;
    unsigned r = v.u + 0x7FFFu + ((v.u >> 16) & 1u);
    return (unsigned short)(r >> 16);
}
__device__ __forceinline__ float bf2f(unsigned short u) {
    union { unsigned u; float f; } v; v.u = ((unsigned)u) << 16; return v.f;
}
// round-to-nearest split (used where staging is one-shot)
__device__ __forceinline__ void split3(float x, unsigned short& h, unsigned short& m, unsigned short& l) {
    h = f2bf(x);
    float r1 = x - bf2f(h);
    m = f2bf(r1);
    float r2 = r1 - bf2f(m);
    l = f2bf(r2);
}
// trunc-based split: hi/mid exact truncation (cheap), lo rne. Residual ~2^-25.
__device__ __forceinline__ void split3t(float x, unsigned short& h, unsigned short& m, unsigned short& l) {
    union { float f; unsigned u; } a; a.f = x;
    h = (unsigned short)(a.u >> 16);
    float r1 = x - bf2f(h);          // exact
    union { float f; unsigned u; } b; b.f = r1;
    m = (unsigned short)(b.u >> 16);
    float r2 = r1 - bf2f(m);         // exact
    l = f2bf(r2);
}

#define MFMA(a, b, c) __builtin_amdgcn_mfma_f32_16x16x32_bf16((a), (b), (c), 0, 0, 0)

#define PSA ((long)NTOK * D_MODEL)       // activation plane stride
#define PSW ((long)D_MODEL * D_MODEL)    // weight plane stride

// ---------------- rmsnorm -> 3 bf16 planes ----------------
__global__ __launch_bounds__(256) void rmsnorm_kernel(const float* __restrict__ x,
    const float* __restrict__ wt, unsigned short* __restrict__ out3)
{
    __shared__ float red[4];
    int n = blockIdx.x;
    int c = threadIdx.x << 2;
    f32x4 v = *(const f32x4*)(x + (long)n*D_MODEL + c);
    float ss = v.x*v.x + v.y*v.y + v.z*v.z + v.w*v.w;
    #pragma unroll
    for (int dd = 32; dd; dd >>= 1) ss += __shfl_xor(ss, dd);
    if ((threadIdx.x & 63) == 0) red[threadIdx.x >> 6] = ss;
    __syncthreads();
    float tot = red[0] + red[1] + red[2] + red[3];
    float rms = rsqrtf(tot * (1.f / D_MODEL) + 1e-6f);
    f32x4 wv = *(const f32x4*)(wt + c);
    f32x4 o = v * rms;
    o = o * wv;
    u16x4 hv, mv, lv;
    #pragma unroll
    for (int j = 0; j < 4; j++) { unsigned short h,m,l; split3(o[j],h,m,l); hv[j]=h; mv[j]=m; lv[j]=l; }
    long idx = (long)n*D_MODEL + c;
    *(u16x4*)(out3 + 0*PSA + idx) = hv;
    *(u16x4*)(out3 + 1*PSA + idx) = mv;
    *(u16x4*)(out3 + 2*PSA + idx) = lv;
}

// ---------------- weight transpose+split: W[K][N] f32 -> out[p][N][K] bf16, 3 weights via z ----------------
__global__ __launch_bounds__(256) void wsplitT_kernel(
    const float* __restrict__ wqs, const float* __restrict__ wks, const float* __restrict__ wvs,
    unsigned short* __restrict__ oq, unsigned short* __restrict__ ok, unsigned short* __restrict__ ov)
{
    __shared__ float t[64][65];
    int k0 = blockIdx.x*64, n0 = blockIdx.y*64, z = blockIdx.z;
    const float* src = (z==0) ? wqs : (z==1) ? wks : wvs;
    unsigned short* dst = (z==0) ? oq : (z==1) ? ok : ov;
    int tid = threadIdx.x;
    int a = tid & 63, g = tid >> 6;
    #pragma unroll 4
    for (int i = 0; i < 16; i++) {
        int k = g*16 + i;
        t[k][a] = src[(long)(k0+k)*D_MODEL + n0 + a];
    }
    __syncthreads();
    #pragma unroll 4
    for (int i = 0; i < 16; i++) {
        int n = g*16 + i;
        float v = t[a][n];               // k = a
        unsigned short h,m,l; split3(v,h,m,l);
        long idx = (long)(n0+n)*D_MODEL + k0 + a;
        dst[0*PSW + idx] = h;
        dst[1*PSW + idx] = m;
        dst[2*PSW + idx] = l;
    }
}

// ---------------- QKV MULTI: A planes x W planes -> f32 out (64x64 tile, 4 blk/CU) ----------------
__global__ __launch_bounds__(256, 4) void qkv_kernel(
    const unsigned short* __restrict__ A3,
    const unsigned short* __restrict__ Wq3, const unsigned short* __restrict__ Wk3,
    const unsigned short* __restrict__ Wv3,
    float* __restrict__ qf, float* __restrict__ kf, float* __restrict__ vf)
{
    __shared__ __align__(16) unsigned short As[3][64*LDSS];
    __shared__ __align__(16) unsigned short Bs[3][64*LDSS];
    int z = blockIdx.z;
    const unsigned short* B3 = (z==0) ? Wq3 : (z==1) ? Wk3 : Wv3;
    float* out = (z==0) ? qf : (z==1) ? kf : vf;
    int n0 = blockIdx.x*64, m0 = blockIdx.y*64;
    int tid = threadIdx.x, w = tid >> 6, lane = tid & 63;
    int wm = (w >> 1)*32, wn = (w & 1)*32;
    int lr = lane & 15, lg = lane >> 4;
    f32x4 zero = {0.f,0.f,0.f,0.f};
    f32x4 acc[2][2];
    #pragma unroll
    for (int mi = 0; mi < 2; mi++)
        #pragma unroll
        for (int ni = 0; ni < 2; ni++) acc[mi][ni] = zero;
    int rb = tid >> 3, kc = (tid & 7) << 2;

    for (int k0 = 0; k0 < D_MODEL; k0 += 32) {
        #pragma unroll
        for (int p = 0; p < 2; p++) {
            int r = p*32 + rb;
            #pragma unroll
            for (int s = 0; s < 3; s++) {
                *(u16x4*)&As[s][r*LDSS + kc] = *(const u16x4*)(A3 + s*PSA + (long)(m0+r)*D_MODEL + k0 + kc);
                *(u16x4*)&Bs[s][r*LDSS + kc] = *(const u16x4*)(B3 + s*PSW + (long)(n0+r)*D_MODEL + k0 + kc);
            }
        }
        __syncthreads();
        bf16x8 bf[3][2];
        #pragma unroll
        for (int s = 0; s < 3; s++)
            #pragma unroll
            for (int ni = 0; ni < 2; ni++)
                bf[s][ni] = *(const bf16x8*)&Bs[s][(wn + ni*16 + lr)*LDSS + lg*8];
        #pragma unroll
        for (int mi = 0; mi < 2; mi++) {
            bf16x8 ah = *(const bf16x8*)&As[0][(wm + mi*16 + lr)*LDSS + lg*8];
            bf16x8 am = *(const bf16x8*)&As[1][(wm + mi*16 + lr)*LDSS + lg*8];
            bf16x8 al = *(const bf16x8*)&As[2][(wm + mi*16 + lr)*LDSS + lg*8];
            #pragma unroll
            for (int ni = 0; ni < 2; ni++) {
                acc[mi][ni] = MFMA(ah, bf[0][ni], acc[mi][ni]);
                acc[mi][ni] = MFMA(ah, bf[1][ni], acc[mi][ni]);
                acc[mi][ni] = MFMA(am, bf[0][ni], acc[mi][ni]);
                acc[mi][ni] = MFMA(ah, bf[2][ni], acc[mi][ni]);
                acc[mi][ni] = MFMA(am, bf[1][ni], acc[mi][ni]);
                acc[mi][ni] = MFMA(al, bf[0][ni], acc[mi][ni]);
            }
        }
        __syncthreads();
    }
    #pragma unroll
    for (int mi = 0; mi < 2; mi++)
        #pragma unroll
        for (int r = 0; r < 4; r++) {
            long row = m0 + wm + mi*16 + lg*4 + r;
            #pragma unroll
            for (int ni = 0; ni < 2; ni++) {
                int col = n0 + wn + ni*16 + lr;
                out[row*D_MODEL + col] = acc[mi][ni][r];
            }
        }
}

// ---------------- WO: reg-prefetch + trunc-split, h += (64x64 tile) ----------------
__global__ __launch_bounds__(256, 3) void wo_kernel(
    const float* __restrict__ A, const float* __restrict__ B, float* h)
{
    __shared__ __align__(16) unsigned short As[3][64*LDSS];
    __shared__ __align__(16) unsigned short Bs[3][64*LDSS];
    int n0 = blockIdx.x*64, m0 = blockIdx.y*64;
    int tid = threadIdx.x, w = tid >> 6, lane = tid & 63;
    int wm = (w >> 1)*32, wn = (w & 1)*32;
    int lr = lane & 15, lg = lane >> 4;
    f32x4 zero = {0.f,0.f,0.f,0.f};
    f32x4 acc[2][2];
    #pragma unroll
    for (int mi = 0; mi < 2; mi++)
        #pragma unroll
        for (int ni = 0; ni < 2; ni++) acc[mi][ni] = zero;
    int rb = tid >> 3, kc = (tid & 7) << 2;          // A staging
    int nb = (tid & 31) << 1, kb = (tid >> 5) << 2;  // B staging

    f32x4 pAv[2];
    f32x2 pBv[4];
    #pragma unroll
    for (int p = 0; p < 2; p++)
        pAv[p] = *(const f32x4*)(A + (long)(m0 + p*32 + rb)*D_MODEL + kc);
    #pragma unroll
    for (int i = 0; i < 4; i++)
        pBv[i] = *(const f32x2*)(B + (long)(kb + i)*D_MODEL + n0 + nb);

    for (int k0 = 0; k0 < D_MODEL; k0 += 32) {
        int kn = k0 + 32;
        #pragma unroll
        for (int p = 0; p < 2; p++) {
            int r = p*32 + rb;
            u16x4 hv, mv, lv;
            #pragma unroll
            for (int j = 0; j < 4; j++) { unsigned short h,m,l; split3t(pAv[p][j],h,m,l); hv[j]=h; mv[j]=m; lv[j]=l; }
            *(u16x4*)&As[0][r*LDSS + kc] = hv;
            *(u16x4*)&As[1][r*LDSS + kc] = mv;
            *(u16x4*)&As[2][r*LDSS + kc] = lv;
        }
        #pragma unroll
        for (int i = 0; i < 2; i++) {
            int r = nb + i;
            u16x4 hv, mv, lv;
            unsigned short h,m,l;
            split3t(pBv[0][i],h,m,l); hv[0]=h; mv[0]=m; lv[0]=l;
            split3t(pBv[1][i],h,m,l); hv[1]=h; mv[1]=m; lv[1]=l;
            split3t(pBv[2][i],h,m,l); hv[2]=h; mv[2]=m; lv[2]=l;
            split3t(pBv[3][i],h,m,l); hv[3]=h; mv[3]=m; lv[3]=l;
            *(u16x4*)&Bs[0][r*LDSS + kb] = hv;
            *(u16x4*)&Bs[1][r*LDSS + kb] = mv;
            *(u16x4*)&Bs[2][r*LDSS + kb] = lv;
        }
        if (kn < D_MODEL) {
            #pragma unroll
            for (int p = 0; p < 2; p++)
                pAv[p] = *(const f32x4*)(A + (long)(m0 + p*32 + rb)*D_MODEL + kn + kc);
            #pragma unroll
            for (int i = 0; i < 4; i++)
                pBv[i] = *(const f32x2*)(B + (long)(kn + kb + i)*D_MODEL + n0 + nb);
        }
        __syncthreads();
        bf16x8 bf[3][2];
        #pragma unroll
        for (int s = 0; s < 3; s++)
            #pragma unroll
            for (int ni = 0; ni < 2; ni++)
                bf[s][ni] = *(const bf16x8*)&Bs[s][(wn + ni*16 + lr)*LDSS + lg*8];
        #pragma unroll
        for (int mi = 0; mi < 2; mi++) {
            bf16x8 ah = *(const bf16x8*)&As[0][(wm + mi*16 + lr)*LDSS + lg*8];
            bf16x8 am = *(const bf16x8*)&As[1][(wm + mi*16 + lr)*LDSS + lg*8];
            bf16x8 al = *(const bf16x8*)&As[2][(wm + mi*16 + lr)*LDSS + lg*8];
            #pragma unroll
            for (int ni = 0; ni < 2; ni++) {
                acc[mi][ni] = MFMA(ah, bf[0][ni], acc[mi][ni]);
                acc[mi][ni] = MFMA(ah, bf[1][ni], acc[mi][ni]);
                acc[mi][ni] = MFMA(am, bf[0][ni], acc[mi][ni]);
                acc[mi][ni] = MFMA(ah, bf[2][ni], acc[mi][ni]);
                acc[mi][ni] = MFMA(am, bf[1][ni], acc[mi][ni]);
                acc[mi][ni] = MFMA(al, bf[0][ni], acc[mi][ni]);
            }
        }
        __syncthreads();
    }
    #pragma unroll
    for (int mi = 0; mi < 2; mi++)
        #pragma unroll
        for (int r = 0; r < 4; r++) {
            long row = m0 + wm + mi*16 + lg*4 + r;
            #pragma unroll
            for (int ni = 0; ni < 2; ni++) {
                int col = n0 + wn + ni*16 + lr;
                h[row*D_MODEL + col] += acc[mi][ni][r];
            }
        }
}

// ---------------- fused MoE w1/w3: 64x128 tile, reg-prefetch + trunc-split ----------------
template<int SPLIT>
__global__ __launch_bounds__(256, 3) void moe13_kernel(
    const unsigned short* __restrict__ A3, const float* __restrict__ W1,
    const float* __restrict__ W3, float* __restrict__ G,
    const int* __restrict__ rowidx, const int* __restrict__ counts,
    const int* __restrict__ offsets)
{
    __shared__ __align__(16) unsigned short As[SPLIT][64*LDSS];
    __shared__ __align__(16) unsigned short Bs[SPLIT][128*LDSS];
    int e = blockIdx.z;
    int cnt = counts[e], off = offsets[e];
    int n0 = blockIdx.x*128, m0 = blockIdx.y*64;
    if (m0 >= cnt) return;
    const float* b1p = W1 + (long)e * (D_MODEL*FFH);
    const float* b3p = W3 + (long)e * (D_MODEL*FFH);
    int tid = threadIdx.x, w = tid >> 6, lane = tid & 63;
    int wm = (w >> 1)*32, wn = (w & 1)*64;
    int lr = lane & 15, lg = lane >> 4;
    f32x4 zero = {0.f,0.f,0.f,0.f};
    f32x4 a1[2][4], a3[2][4];
    #pragma unroll
    for (int mi = 0; mi < 2; mi++)
        #pragma unroll
        for (int ni = 0; ni < 4; ni++) { a1[mi][ni] = zero; a3[mi][ni] = zero; }
    int rb = tid >> 3, kc = (tid & 7) << 2;

    // hoisted row gather info
    long arow[2]; int av[2];
    #pragma unroll
    for (int p = 0; p < 2; p++) {
        int r = p*32 + rb;
        av[p] = (m0 + r < cnt) ? 1 : 0;
        arow[p] = av[p] ? (long)rowidx[off + m0 + r] : 0;
    }
    u16x4 z4 = {0,0,0,0};
    u16x4 pA[2][SPLIT];
    f32x4 p1[4], p3[4];
    #pragma unroll
    for (int p = 0; p < 2; p++)
        #pragma unroll
        for (int s = 0; s < SPLIT; s++)
            pA[p][s] = av[p] ? *(const u16x4*)(A3 + s*PSA + arow[p]*D_MODEL + kc) : z4;
    #pragma unroll
    for (int i = 0; i < 4; i++) {
        p1[i] = *(const f32x4*)(b1p + (long)(kc + i)*FFH + n0 + rb*4);
        p3[i] = *(const f32x4*)(b3p + (long)(kc + i)*FFH + n0 + rb*4);
    }

    for (int k0 = 0; k0 < D_MODEL; k0 += 32) {
        int kn = k0 + 32;
        // stage A from prefetched regs
        #pragma unroll
        for (int p = 0; p < 2; p++)
            #pragma unroll
            for (int s = 0; s < SPLIT; s++)
                *(u16x4*)&As[s][(p*32 + rb)*LDSS + kc] = pA[p][s];
        // stage B (w1) from p1
        #pragma unroll
        for (int i = 0; i < 4; i++) {
            int r = rb*4 + i;
            if (SPLIT == 3) {
                u16x4 hv, mv, lv;
                unsigned short h,m,l;
                split3t(p1[0][i],h,m,l); hv[0]=h; mv[0]=m; lv[0]=l;
                split3t(p1[1][i],h,m,l); hv[1]=h; mv[1]=m; lv[1]=l;
                split3t(p1[2][i],h,m,l); hv[2]=h; mv[2]=m; lv[2]=l;
                split3t(p1[3][i],h,m,l); hv[3]=h; mv[3]=m; lv[3]=l;
                *(u16x4*)&Bs[0][r*LDSS + kc] = hv;
                *(u16x4*)&Bs[1][r*LDSS + kc] = mv;
                *(u16x4*)&Bs[2][r*LDSS + kc] = lv;
            } else {
                u16x4 hv = {f2bf(p1[0][i]), f2bf(p1[1][i]), f2bf(p1[2][i]), f2bf(p1[3][i])};
                *(u16x4*)&Bs[0][r*LDSS + kc] = hv;
            }
        }
        // prefetch next-iter A and w1 (in flight across 2 MFMA phases)
        if (kn < D_MODEL) {
            #pragma unroll
            for (int p = 0; p < 2; p++)
                #pragma unroll
                for (int s = 0; s < SPLIT; s++)
                    pA[p][s] = av[p] ? *(const u16x4*)(A3 + s*PSA + arow[p]*D_MODEL + kn + kc) : z4;
            #pragma unroll
            for (int i = 0; i < 4; i++)
                p1[i] = *(const f32x4*)(b1p + (long)(kn + kc + i)*FFH + n0 + rb*4);
        }
        __syncthreads();
        {
            bf16x8 bf[SPLIT][4];
            #pragma unroll
            for (int s = 0; s < SPLIT; s++)
                #pragma unroll
                for (int ni = 0; ni < 4; ni++)
                    bf[s][ni] = *(const bf16x8*)&Bs[s][(wn + ni*16 + lr)*LDSS + lg*8];
            #pragma unroll
            for (int mi = 0; mi < 2; mi++) {
                bf16x8 ah = *(const bf16x8*)&As[0][(wm + mi*16 + lr)*LDSS + lg*8];
                #pragma unroll
                for (int ni = 0; ni < 4; ni++) {
                    f32x4 a = a1[mi][ni];
                    a = MFMA(ah, bf[0][ni], a);
                    if (SPLIT == 3) {
                        bf16x8 am = *(const bf16x8*)&As[1][(wm + mi*16 + lr)*LDSS + lg*8];
                        bf16x8 al = *(const bf16x8*)&As[2][(wm + mi*16 + lr)*LDSS + lg*8];
                        a = MFMA(ah, bf[1][ni], a);
                        a = MFMA(am, bf[0][ni], a);
                        a = MFMA(ah, bf[2][ni], a);
                        a = MFMA(am, bf[1][ni], a);
                        a = MFMA(al, bf[0][ni], a);
                    }
                    a1[mi][ni] = a;
                }
            }
        }
        __syncthreads();
        // stage B (w3) from p3
        #pragma unroll
        for (int i = 0; i < 4; i++) {
            int r = rb*4 + i;
            if (SPLIT == 3) {
                u16x4 hv, mv, lv;
                unsigned short h,m,l;
                split3t(p3[0][i],h,m,l); hv[0]=h; mv[0]=m; lv[0]=l;
                split3t(p3[1][i],h,m,l); hv[1]=h; mv[1]=m; lv[1]=l;
                split3t(p3[2][i],h,m,l); hv[2]=h; mv[2]=m; lv[2]=l;
                split3t(p3[3][i],h,m,l); hv[3]=h; mv[3]=m; lv[3]=l;
                *(u16x4*)&Bs[0][r*LDSS + kc] = hv;
                *(u16x4*)&Bs[1][r*LDSS + kc] = mv;
                *(u16x4*)&Bs[2][r*LDSS + kc] = lv;
            } else {
                u16x4 hv = {f2bf(p3[0][i]), f2bf(p3[1][i]), f2bf(p3[2][i]), f2bf(p3[3][i])};
                *(u16x4*)&Bs[0][r*LDSS + kc] = hv;
            }
        }
        if (kn < D_MODEL) {
            #pragma unroll
            for (int i = 0; i < 4; i++)
                p3[i] = *(const f32x4*)(b3p + (long)(kn + kc + i)*FFH + n0 + rb*4);
        }
        __syncthreads();
        {
            bf16x8 bf[SPLIT][4];
            #pragma unroll
            for (int s = 0; s < SPLIT; s++)
                #pragma unroll
                for (int ni = 0; ni < 4; ni++)
                    bf[s][ni] = *(const bf16x8*)&Bs[s][(wn + ni*16 + lr)*LDSS + lg*8];
            #pragma unroll
            for (int mi = 0; mi < 2; mi++) {
                bf16x8 ah = *(const bf16x8*)&As[0][(wm + mi*16 + lr)*LDSS + lg*8];
                #pragma unroll
                for (int ni = 0; ni < 4; ni++) {
                    f32x4 a = a3[mi][ni];
                    a = MFMA(ah, bf[0][ni], a);
                    if (SPLIT == 3) {
                        bf16x8 am = *(const bf16x8*)&As[1][(wm + mi*16 + lr)*LDSS + lg*8];
                        bf16x8 al = *(const bf16x8*)&As[2][(wm + mi*16 + lr)*LDSS + lg*8];
                        a = MFMA(ah, bf[1][ni], a);
                        a = MFMA(am, bf[0][ni], a);
                        a = MFMA(ah, bf[2][ni], a);
                        a = MFMA(am, bf[1][ni], a);
                        a = MFMA(al, bf[0][ni], a);
                    }
                    a3[mi][ni] = a;
                }
            }
        }
        __syncthreads();
    }
    #pragma unroll
    for (int mi = 0; mi < 2; mi++)
        #pragma unroll
        for (int r = 0; r < 4; r++) {
            int rowl = wm + mi*16 + lg*4 + r;
            if (m0 + rowl < cnt) {
                long crow = off + m0 + rowl;
                #pragma unroll
                for (int ni = 0; ni < 4; ni++) {
                    int col = n0 + wn + ni*16 + lr;
                    float v1 = a1[mi][ni][r];
                    float v3 = a3[mi][ni][r];
                    G[crow*FFH + col] = (v1 / (1.f + expf(-v1))) * v3;
                }
            }
        }
}

// ---------------- w2: 64x64 tile, reg-prefetch + trunc-split, weighted atomic into h ----------------
template<int SPLIT>
__global__ __launch_bounds__(256, 4) void w2_kernel(
    const float* __restrict__ G, const float* __restrict__ W2, float* h,
    const int* __restrict__ rowidx, const float* __restrict__ wrow,
    const int* __restrict__ counts, const int* __restrict__ offsets)
{
    __shared__ __align__(16) unsigned short As[SPLIT][64*LDSS];
    __shared__ __align__(16) unsigned short Bs[SPLIT][64*LDSS];
    int e = blockIdx.z;
    int cnt = counts[e], off = offsets[e];
    int n0 = blockIdx.x*64, m0 = blockIdx.y*64;
    if (m0 >= cnt) return;
    const float* bp = W2 + (long)e * (FFH*D_MODEL);
    int tid = threadIdx.x, w = tid >> 6, lane = tid & 63;
    int wm = (w >> 1)*32, wn = (w & 1)*32;
    int lr = lane & 15, lg = lane >> 4;
    f32x4 zero = {0.f,0.f,0.f,0.f};
    f32x4 acc[2][2];
    #pragma unroll
    for (int mi = 0; mi < 2; mi++)
        #pragma unroll
        for (int ni = 0; ni < 2; ni++) acc[mi][ni] = zero;
    int rb = tid >> 3, kc = (tid & 7) << 2;          // A staging
    int nb = (tid & 31) << 1, kb = (tid >> 5) << 2;  // B staging

    int av[2];
    #pragma unroll
    for (int p = 0; p < 2; p++) av[p] = (m0 + p*32 + rb < cnt) ? 1 : 0;
    f32x4 pG[2];
    f32x2 pW[4];
    #pragma unroll
    for (int p = 0; p < 2; p++)
        pG[p] = av[p] ? *(const f32x4*)(G + (long)(off + m0 + p*32 + rb)*FFH + kc) : zero;
    #pragma unroll
    for (int i = 0; i < 4; i++)
        pW[i] = *(const f32x2*)(bp + (long)(kb + i)*D_MODEL + n0 + nb);

    for (int k0 = 0; k0 < FFH; k0 += 32) {
        int kn = k0 + 32;
        #pragma unroll
        for (int p = 0; p < 2; p++) {
            int r = p*32 + rb;
            if (SPLIT == 3) {
                u16x4 hv, mv, lv;
                #pragma unroll
                for (int j = 0; j < 4; j++) { unsigned short h,m,l; split3t(pG[p][j],h,m,l); hv[j]=h; mv[j]=m; lv[j]=l; }
                *(u16x4*)&As[0][r*LDSS + kc] = hv;
                *(u16x4*)&As[1][r*LDSS + kc] = mv;
                *(u16x4*)&As[2][r*LDSS + kc] = lv;
            } else {
                u16x4 hv;
                #pragma unroll
                for (int j = 0; j < 4; j++) hv[j] = f2bf(pG[p][j]);
                *(u16x4*)&As[0][r*LDSS + kc] = hv;
            }
        }
        #pragma unroll
        for (int i = 0; i < 2; i++) {
            int r = nb + i;
            if (SPLIT == 3) {
                u16x4 hv, mv, lv;
                unsigned short h,m,l;
                split3t(pW[0][i],h,m,l); hv[0]=h; mv[0]=m; lv[0]=l;
                split3t(pW[1][i],h,m,l); hv[1]=h; mv[1]=m; lv[1]=l;
                split3t(pW[2][i],h,m,l); hv[2]=h; mv[2]=m; lv[2]=l;
                split3t(pW[3][i],h,m,l); hv[3]=h; mv[3]=m; lv[3]=l;
                *(u16x4*)&Bs[0][r*LDSS + kb] = hv;
                *(u16x4*)&Bs[1][r*LDSS + kb] = mv;
                *(u16x4*)&Bs[2][r*LDSS + kb] = lv;
            } else {
                u16x4 hv = {f2bf(pW[0][i]), f2bf(pW[1][i]), f2bf(pW[2][i]), f2bf(pW[3][i])};
                *(u16x4*)&Bs[0][r*LDSS + kb] = hv;
            }
        }
        if (kn < FFH) {
            #pragma unroll
            for (int p = 0; p < 2; p++)
                pG[p] = av[p] ? *(const f32x4*)(G + (long)(off + m0 + p*32 + rb)*FFH + kn + kc) : zero;
            #pragma unroll
            for (int i = 0; i < 4; i++)
                pW[i] = *(const f32x2*)(bp + (long)(kn + kb + i)*D_MODEL + n0 + nb);
        }
        __syncthreads();
        bf16x8 bf[SPLIT][2];
        #pragma unroll
        for (int s = 0; s < SPLIT; s++)
            #pragma unroll
            for (int ni = 0; ni < 2; ni++)
                bf[s][ni] = *(const bf16x8*)&Bs[s][(wn + ni*16 + lr)*LDSS + lg*8];
        #pragma unroll
        for (int mi = 0; mi < 2; mi++) {
            bf16x8 ah = *(const bf16x8*)&As[0][(wm + mi*16 + lr)*LDSS + lg*8];
            #pragma unroll
            for (int ni = 0; ni < 2; ni++) {
                acc[mi][ni] = MFMA(ah, bf[0][ni], acc[mi][ni]);
                if (SPLIT == 3) {
                    bf16x8 am = *(const bf16x8*)&As[1][(wm + mi*16 + lr)*LDSS + lg*8];
                    bf16x8 al = *(const bf16x8*)&As[2][(wm + mi*16 + lr)*LDSS + lg*8];
                    acc[mi][ni] = MFMA(ah, bf[1][ni], acc[mi][ni]);
                    acc[mi][ni] = MFMA(am, bf[0][ni], acc[mi][ni]);
                    acc[mi][ni] = MFMA(ah, bf[2][ni], acc[mi][ni]);
                    acc[mi][ni] = MFMA(am, bf[1][ni], acc[mi][ni]);
                    acc[mi][ni] = MFMA(al, bf[0][ni], acc[mi][ni]);
                }
            }
        }
        __syncthreads();
    }
    #pragma unroll
    for (int mi = 0; mi < 2; mi++)
        #pragma unroll
        for (int r = 0; r < 4; r++) {
            int rowl = wm + mi*16 + lg*4 + r;
            if (m0 + rowl < cnt) {
                long crow = off + m0 + rowl;
                long n = rowidx[crow];
                float wgt = wrow[crow];
                #pragma unroll
                for (int ni = 0; ni < 2; ni++) {
                    int col = n0 + wn + ni*16 + lr;
                    atomicAdd(&h[n*D_MODEL + col], wgt * acc[mi][ni][r]);
                }
            }
        }
}

// ---------------- flash attention (f32 q/k/v, trunc-split inside) ----------------
__global__ __launch_bounds__(256) void attn_kernel(
    const float* __restrict__ q, const float* __restrict__ k,
    const float* __restrict__ v, float* __restrict__ att)
{
    __shared__ __align__(16) unsigned short Qs[3][64*72];
    __shared__ __align__(16) unsigned short KP[3][2560];
    __shared__ __align__(16) unsigned short Vt[3][2560];

    int qt = blockIdx.x, bh = blockIdx.y;
    int b = bh >> 4, hh = bh & 15;
    int tid = threadIdx.x, w = tid >> 6, lane = tid & 63;
    int lr = lane & 15, lg = lane >> 4;
    int lrow = tid >> 4;
    int lcol = (tid & 15) << 2;

    const float* qbase = q + ((long)(b*SEQ + qt*64) * D_MODEL + hh*64);
    #pragma unroll
    for (int p = 0; p < 4; p++) {
        int r = p*16 + lrow;
        f32x4 vv = *(const f32x4*)(qbase + (long)r * D_MODEL + lcol);
        #pragma unroll
        for (int jj = 0; jj < 4; jj++) {
            unsigned short h,m,l; split3t(vv[jj],h,m,l);
            Qs[0][r*72 + lcol + jj] = h;
            Qs[1][r*72 + lcol + jj] = m;
            Qs[2][r*72 + lcol + jj] = l;
        }
    }

    f32x4 zero = {0.f,0.f,0.f,0.f};
    f32x4 oacc[4] = {zero, zero, zero, zero};
    float mrun[4] = {-INFINITY,-INFINITY,-INFINITY,-INFINITY};
    float lrun[4] = {0.f,0.f,0.f,0.f};

    int ntile = 2*qt + 2;
    for (int jt = 0; jt < ntile; jt++) {
        const float* kbase = k + ((long)(b*SEQ + jt*32) * D_MODEL + hh*64);
        const float* vbase = v + ((long)(b*SEQ + jt*32) * D_MODEL + hh*64);
        #pragma unroll
        for (int p = 0; p < 2; p++) {
            int r = p*16 + lrow;
            f32x4 kv4 = *(const f32x4*)(kbase + (long)r * D_MODEL + lcol);
            f32x4 vv4 = *(const f32x4*)(vbase + (long)r * D_MODEL + lcol);
            #pragma unroll
            for (int jj = 0; jj < 4; jj++) {
                unsigned short h,m,l;
                split3t(kv4[jj],h,m,l);
                KP[0][r*72 + lcol + jj] = h;
                KP[1][r*72 + lcol + jj] = m;
                KP[2][r*72 + lcol + jj] = l;
                split3t(vv4[jj],h,m,l);
                Vt[0][(lcol+jj)*40 + r] = h;
                Vt[1][(lcol+jj)*40 + r] = m;
                Vt[2][(lcol+jj)*40 + r] = l;
            }
        }
        __syncthreads();

        f32x4 s[2] = {zero, zero};
        #pragma unroll
        for (int ks = 0; ks < 2; ks++) {
            bf16x8 qh = *(const bf16x8*)&Qs[0][(w*16 + lr)*72 + ks*32 + lg*8];
            bf16x8 qm = *(const bf16x8*)&Qs[1][(w*16 + lr)*72 + ks*32 + lg*8];
            bf16x8 ql = *(const bf16x8*)&Qs[2][(w*16 + lr)*72 + ks*32 + lg*8];
            #pragma unroll
            for (int ni = 0; ni < 2; ni++) {
                bf16x8 kh = *(const bf16x8*)&KP[0][(ni*16 + lr)*72 + ks*32 + lg*8];
                bf16x8 km = *(const bf16x8*)&KP[1][(ni*16 + lr)*72 + ks*32 + lg*8];
                bf16x8 kl = *(const bf16x8*)&KP[2][(ni*16 + lr)*72 + ks*32 + lg*8];
                s[ni] = MFMA(qh, kh, s[ni]);
                s[ni] = MFMA(qh, km, s[ni]);
                s[ni] = MFMA(qm, kh, s[ni]);
                s[ni] = MFMA(qh, kl, s[ni]);
                s[ni] = MFMA(qm, km, s[ni]);
                s[ni] = MFMA(ql, kh, s[ni]);
            }
        }
        __syncthreads();

        #pragma unroll
        for (int r = 0; r < 4; r++) {
            int qg = qt*64 + w*16 + lg*4 + r;
            float mx = -INFINITY;
            #pragma unroll
            for (int ni = 0; ni < 2; ni++) {
                int kg = jt*32 + ni*16 + lr;
                float val = s[ni][r] * 0.125f;
                if (kg > qg) val = -INFINITY;
                s[ni][r] = val;
                mx = fmaxf(mx, val);
            }
            #pragma unroll
            for (int dd = 1; dd < 16; dd <<= 1)
                mx = fmaxf(mx, __shfl_xor(mx, dd));
            float mnew  = fmaxf(mrun[r], mx);
            float alpha = expf(mrun[r] - mnew);
            float ps = 0.f;
            #pragma unroll
            for (int ni = 0; ni < 2; ni++) {
                float pv = expf(s[ni][r] - mnew);
                s[ni][r] = pv;
                ps += pv;
            }
            #pragma unroll
            for (int dd = 1; dd < 16; dd <<= 1)
                ps += __shfl_xor(ps, dd);
            lrun[r] = lrun[r] * alpha + ps;
            mrun[r] = mnew;
            #pragma unroll
            for (int d = 0; d < 4; d++) oacc[d][r] *= alpha;
            int prow = w*16 + lg*4 + r;
            #pragma unroll
            for (int ni = 0; ni < 2; ni++) {
                unsigned short h,m,l; split3t(s[ni][r],h,m,l);
                KP[0][prow*40 + ni*16 + lr] = h;
                KP[1][prow*40 + ni*16 + lr] = m;
                KP[2][prow*40 + ni*16 + lr] = l;
            }
        }
        {
            bf16x8 ph = *(const bf16x8*)&KP[0][(w*16 + lr)*40 + lg*8];
            bf16x8 pm = *(const bf16x8*)&KP[1][(w*16 + lr)*40 + lg*8];
            bf16x8 pl = *(const bf16x8*)&KP[2][(w*16 + lr)*40 + lg*8];
            #pragma unroll
            for (int ni = 0; ni < 4; ni++) {
                bf16x8 vh = *(const bf16x8*)&Vt[0][(ni*16 + lr)*40 + lg*8];
                bf16x8 vm = *(const bf16x8*)&Vt[1][(ni*16 + lr)*40 + lg*8];
                bf16x8 vl = *(const bf16x8*)&Vt[2][(ni*16 + lr)*40 + lg*8];
                oacc[ni] = MFMA(ph, vh, oacc[ni]);
                oacc[ni] = MFMA(ph, vm, oacc[ni]);
                oacc[ni] = MFMA(pm, vh, oacc[ni]);
                oacc[ni] = MFMA(ph, vl, oacc[ni]);
                oacc[ni] = MFMA(pm, vm, oacc[ni]);
                oacc[ni] = MFMA(pl, vh, oacc[ni]);
            }
        }
        __syncthreads();
    }
    float* obase = att + ((long)(b*SEQ + qt*64) * D_MODEL + hh*64);
    #pragma unroll
    for (int r = 0; r < 4; r++) {
        float inv = 1.f / lrun[r];
        #pragma unroll
        for (int ni = 0; ni < 4; ni++)
            obase[(long)(w*16 + lg*4 + r) * D_MODEL + ni*16 + lr] = oacc[ni][r] * inv;
    }
}

// ---------------- logits: A plane0 x B=emb (BT), f32 out ----------------
__global__ __launch_bounds__(256) void logits_kernel(
    const unsigned short* __restrict__ A0, const float* __restrict__ Bmat, float* __restrict__ C)
{
    __shared__ __align__(16) unsigned short As[128*LDSS];
    __shared__ __align__(16) unsigned short Bs[128*LDSS];
    int n0 = blockIdx.y * 128;   // vocab
    int m0 = blockIdx.x * 128;   // tokens
    int tid = threadIdx.x, w = tid >> 6, lane = tid & 63;
    int wm = (w >> 1)*64, wn = (w & 1)*64;
    int lr = lane & 15, lg = lane >> 4;
    f32x4 zero = {0.f,0.f,0.f,0.f};
    f32x4 acc[4][4];
    #pragma unroll
    for (int mi = 0; mi < 4; mi++)
        #pragma unroll
        for (int ni = 0; ni < 4; ni++) acc[mi][ni] = zero;
    int rb = tid >> 3, kc = (tid & 7) << 2;
    for (int k0 = 0; k0 < D_MODEL; k0 += 32) {
        #pragma unroll
        for (int p = 0; p < 4; p++) {
            int r = p*32 + rb;
            *(u16x4*)&As[r*LDSS + kc] = *(const u16x4*)(A0 + (long)(m0+r)*D_MODEL + k0 + kc);
            f32x4 vv = *(const f32x4*)(Bmat + (long)(n0+r)*D_MODEL + k0 + kc);
            u16x4 hv;
            #pragma unroll
            for (int j = 0; j < 4; j++) hv[j] = f2bf(vv[j]);
            *(u16x4*)&Bs[r*LDSS + kc] = hv;
        }
        __syncthreads();
        bf16x8 bfv[4], af[4];
        #pragma unroll
        for (int ni = 0; ni < 4; ni++)
            bfv[ni] = *(const bf16x8*)&Bs[(wn + ni*16 + lr)*LDSS + lg*8];
        #pragma unroll
        for (int mi = 0; mi < 4; mi++)
            af[mi] = *(const bf16x8*)&As[(wm + mi*16 + lr)*LDSS + lg*8];
        #pragma unroll
        for (int mi = 0; mi < 4; mi++)
            #pragma unroll
            for (int ni = 0; ni < 4; ni++)
                acc[mi][ni] = MFMA(af[mi], bfv[ni], acc[mi][ni]);
        __syncthreads();
    }
    #pragma unroll
    for (int mi = 0; mi < 4; mi++)
        #pragma unroll
        for (int r = 0; r < 4; r++) {
            long row = m0 + wm + mi*16 + lg*4 + r;
            #pragma unroll
            for (int ni = 0; ni < 4; ni++) {
                int col = n0 + wn + ni*16 + lr;
                C[row*VOCAB + col] = acc[mi][ni][r];
            }
        }
}

// ---------------- small kernels ----------------
__global__ __launch_bounds__(256) void embed_kernel(const int* __restrict__ tok,
    const float* __restrict__ emb, float* __restrict__ h)
{
    int n = blockIdx.x;
    int c = threadIdx.x << 2;
    long t = tok[n];
    *(f32x4*)(h + (long)n*D_MODEL + c) = *(const f32x4*)(emb + t*D_MODEL + c);
}

__global__ __launch_bounds__(256) void ropetab_kernel(float* __restrict__ tab)
{
    int idx = blockIdx.x * 256 + threadIdx.x;
    if (idx >= SEQ * 32) return;
    int t = idx >> 5, i = idx & 31;
    double inv = pow(10000.0, -(double)(2*i) / 64.0);
    double ang = (double)t * inv;
    tab[idx*2]   = (float)cos(ang);
    tab[idx*2+1] = (float)sin(ang);
}

__global__ __launch_bounds__(256) void rope_kernel(float* __restrict__ q, float* __restrict__ kk,
    const float* __restrict__ tab)
{
    int gid = blockIdx.x * 256 + threadIdx.x;
    if (gid >= NTOK * 512) return;
    int n   = gid >> 9;
    int rem = gid & 511;
    int hh  = rem >> 5;
    int i   = rem & 31;
    int t   = n & (SEQ - 1);
    float cs = tab[(t*32 + i)*2];
    float sn = tab[(t*32 + i)*2 + 1];
    long base = (long)n * D_MODEL + hh*64 + 2*i;
    float qr = q[base], qi = q[base+1];
    q[base]   = qr*cs - qi*sn;
    q[base+1] = qr*sn + qi*cs;
    float kr = kk[base], ki = kk[base+1];
    kk[base]   = kr*cs - ki*sn;
    kk[base+1] = kr*sn + ki*cs;
}

__global__ __launch_bounds__(64) void gate_kernel(const unsigned short* __restrict__ xf3,
    const float* __restrict__ gw, int* __restrict__ counts,
    int* __restrict__ eid, float* __restrict__ wts, float* __restrict__ pbuf)
{
    int n = blockIdx.x;
    int lane = threadIdx.x;
    float acc[8] = {0,0,0,0,0,0,0,0};
    for (int d0 = lane*4; d0 < D_MODEL; d0 += 256) {
        long idx = (long)n*D_MODEL + d0;
        u16x4 xh = *(const u16x4*)(xf3 + 0*PSA + idx);
        u16x4 xm = *(const u16x4*)(xf3 + 1*PSA + idx);
        u16x4 xl = *(const u16x4*)(xf3 + 2*PSA + idx);
        #pragma unroll
        for (int j = 0; j < 4; j++) {
            float xv = bf2f(xh[j]) + bf2f(xm[j]) + bf2f(xl[j]);
            const float* g = gw + (d0+j) * 8;
            #pragma unroll
            for (int e = 0; e < 8; e++) acc[e] += xv * g[e];
        }
    }
    #pragma unroll
    for (int e = 0; e < 8; e++) {
        #pragma unroll
        for (int dd = 32; dd; dd >>= 1) acc[e] += __shfl_xor(acc[e], dd);
    }
    if (lane == 0) {
        float mx = acc[0];
        #pragma unroll
        for (int e = 1; e < 8; e++) mx = fmaxf(mx, acc[e]);
        float pe[8], ssum = 0.f;
        #pragma unroll
        for (int e = 0; e < 8; e++) { pe[e] = expf(acc[e] - mx); ssum += pe[e]; }
        float sinv = 1.f / ssum;
        #pragma unroll
        for (int e = 0; e < 8; e++) { pe[e] *= sinv; pbuf[n*8 + e] = pe[e]; }
        int e1 = 0;
        #pragma unroll
        for (int e = 1; e < 8; e++) if (pe[e] > pe[e1]) e1 = e;
        int e2 = -1;
        #pragma unroll
        for (int e = 0; e < 8; e++) if (e != e1 && (e2 < 0 || pe[e] > pe[e2])) e2 = e;
        float v1 = pe[e1], v2 = pe[e2];
        float wsum = v1 + v2 + 1e-8f;
        eid[n*2] = e1; eid[n*2+1] = e2;
        wts[n*2] = v1 / wsum; wts[n*2+1] = v2 / wsum;
        atomicAdd(counts + e1, 1);
        atomicAdd(counts + e2, 1);
    }
}

__global__ __launch_bounds__(64) void scan_kernel(const int* __restrict__ counts,
    int* __restrict__ offs, int* __restrict__ cursor,
    const float* __restrict__ pbuf, float* __restrict__ aux)
{
    int t = threadIdx.x;
    int e = t & 7, c = t >> 3;
    float s = 0.f;
    for (int n = 0; n < NTOK/8; n++)
        s += pbuf[(c*(NTOK/8) + n)*8 + e];
    #pragma unroll
    for (int dd = 8; dd < 64; dd <<= 1) s += __shfl_xor(s, dd);
    __shared__ float red[8];
    if (t < 8) red[t] = s;
    __syncthreads();
    if (t == 0) {
        int o = 0; float a = 0.f;
        for (int k = 0; k < 8; k++) {
            offs[k] = o; cursor[k] = o; o += counts[k];
            a += (float)counts[k] * red[k];
        }
        aux[0] += 8.f * a / ((float)NTOK * (float)NTOK);
    }
}

__global__ __launch_bounds__(256) void assign_kernel(const int* __restrict__ eid,
    const float* __restrict__ wts, int* __restrict__ cursor,
    int* __restrict__ rowidx, float* __restrict__ wrow)
{
    int n = blockIdx.x * 256 + threadIdx.x;
    if (n >= NTOK) return;
    #pragma unroll
    for (int s = 0; s < 2; s++) {
        int e = eid[n*2 + s];
        int p = atomicAdd(cursor + e, 1);
        rowidx[p] = n;
        wrow[p] = wts[n*2 + s];
    }
}

__global__ void write_aux_kernel(float* __restrict__ out, const float* __restrict__ aux)
{
    if (threadIdx.x == 0 && blockIdx.x == 0)
        out[(long)NTOK * VOCAB] = aux[0];
}

// ---------------- launch ----------------
extern "C" void kernel_launch(void* const* d_in, const int* in_sizes, int n_in,
                              void* d_out, int out_size, void* d_ws, size_t ws_size,
                              hipStream_t stream)
{
    const int*   tokens = (const int*)d_in[0];
    const float* emb    = (const float*)d_in[1];
    const float* anw    = (const float*)d_in[2];
    const float* wq     = (const float*)d_in[3];
    const float* wk     = (const float*)d_in[4];
    const float* wv     = (const float*)d_in[5];
    const float* wo     = (const float*)d_in[6];
    const float* fnw    = (const float*)d_in[7];
    const float* gw     = (const float*)d_in[8];
    const float* w1     = (const float*)d_in[9];
    const float* w2     = (const float*)d_in[10];
    const float* w3     = (const float*)d_in[11];
    const float* finw   = (const float*)d_in[12];
    float* out = (float*)d_out;

    char* W = (char*)d_ws;
    const size_t MB = 1024u * 1024u;
    // ctrl block [0, 1MB)
    int*   counts = (int*)(W + 0);
    int*   offs   = (int*)(W + 64);
    int*   cursor = (int*)(W + 128);
    float* aux    = (float*)(W + 192);
    int*   eid    = (int*)(W + 4096);
    float* wts    = (float*)(W + 4096 + 16384);
    int*   rowix  = (int*)(W + 4096 + 32768);
    float* wrow   = (float*)(W + 4096 + 49152);
    float* pbuf   = (float*)(W + 4096 + 65536);
    float* rtab   = (float*)(W + 4096 + 131072 + 65536);
    // big buffers — lifetimes:
    //   wq3/wk3/wv3 [45,63) live wsplitT -> qkv
    //   att [45,53) live attn -> wo (weight planes dead)
    //   g [21,53) MoE phase (qkv f32 + att dead)
    // peak 63 MB
    float*          h    = (float*)(W + 1*MB);                   // [1,9)
    unsigned short* hn3  = (unsigned short*)(W + 9*MB);          // [9,21)
    float*          qf   = (float*)(W + 21*MB);                  // [21,29)
    float*          kf   = (float*)(W + 29*MB);                  // [29,37)
    float*          vf   = (float*)(W + 37*MB);                  // [37,45)
    unsigned short* wq3  = (unsigned short*)(W + 45*MB);         // [45,51)
    unsigned short* wk3  = (unsigned short*)(W + 51*MB);         // [51,57)
    unsigned short* wv3  = (unsigned short*)(W + 57*MB);         // [57,63)
    float*          att  = (float*)(W + 45*MB);                  // [45,53)
    float*          g    = (float*)(W + 21*MB);                  // [21,53) MoE phase

    hipMemsetAsync(W, 0, 256, stream);
    ropetab_kernel<<<(SEQ*32 + 255)/256, 256, 0, stream>>>(rtab);
    embed_kernel<<<NTOK, 256, 0, stream>>>(tokens, emb, h);

    for (int l = 0; l < 2; l++) {
        const float* wql = wq + (size_t)l*D_MODEL*D_MODEL;
        const float* wkl = wk + (size_t)l*D_MODEL*D_MODEL;
        const float* wvl = wv + (size_t)l*D_MODEL*D_MODEL;
        const float* wol = wo + (size_t)l*D_MODEL*D_MODEL;

        rmsnorm_kernel<<<NTOK, 256, 0, stream>>>(h, anw + (size_t)l*D_MODEL, hn3);
        wsplitT_kernel<<<dim3(16, 16, 3), 256, 0, stream>>>(wql, wkl, wvl, wq3, wk3, wv3);
        qkv_kernel<<<dim3(D_MODEL/64, NTOK/64, 3), 256, 0, stream>>>(hn3, wq3, wk3, wv3, qf, kf, vf);
        rope_kernel<<<(NTOK*512 + 255)/256, 256, 0, stream>>>(qf, kf, rtab);
        attn_kernel<<<dim3(SEQ/64, BATCH*NHEADS), 256, 0, stream>>>(qf, kf, vf, att);
        wo_kernel<<<dim3(D_MODEL/64, NTOK/64), 256, 0, stream>>>(att, wol, h);

        rmsnorm_kernel<<<NTOK, 256, 0, stream>>>(h, fnw + (size_t)l*D_MODEL, hn3);
        hipMemsetAsync(W, 0, 160, stream);   // counts/offs/cursor (aux preserved @192)
        gate_kernel<<<NTOK, 64, 0, stream>>>(hn3, gw + (size_t)l*D_MODEL*NEXP, counts, eid, wts, pbuf);
        scan_kernel<<<1, 64, 0, stream>>>(counts, offs, cursor, pbuf, aux);
        assign_kernel<<<(NTOK + 255)/256, 256, 0, stream>>>(eid, wts, cursor, rowix, wrow);

        const float* w1l = w1 + (size_t)l*NEXP*D_MODEL*FFH;
        const float* w3l = w3 + (size_t)l*NEXP*D_MODEL*FFH;
        const float* w2l = w2 + (size_t)l*NEXP*FFH*D_MODEL;
        dim3 g13(FFH/128, 2*NTOK/64, NEXP);
        dim3 g2d(D_MODEL/64, 2*NTOK/64, NEXP);
        if (l == 0) {
            moe13_kernel<3><<<g13, 256, 0, stream>>>(hn3, w1l, w3l, g, rowix, counts, offs);
            w2_kernel<3><<<g2d, 256, 0, stream>>>(g, w2l, h, rowix, wrow, counts, offs);
        } else {
            moe13_kernel<1><<<g13, 256, 0, stream>>>(hn3, w1l, w3l, g, rowix, counts, offs);
            w2_kernel<1><<<g2d, 256, 0, stream>>>(g, w2l, h, rowix, wrow, counts, offs);
        }
    }

    rmsnorm_kernel<<<NTOK, 256, 0, stream>>>(h, finw, hn3);
    logits_kernel<<<dim3(NTOK/128, VOCAB/128), 256, 0, stream>>>(hn3, emb, out);
    write_aux_kernel<<<1, 1, 0, stream>>>(out, aux);
}

// Round 9
// 1975.163 us; speedup vs baseline: 1.0616x; 1.0616x over previous
//
#include <hip/hip_runtime.h>
#include <hip/hip_bf16.h>
#include <math.h>

#define D_MODEL 1024
#define NHEADS  16
#define HDIM    64
#define NEXP    8
#define FFH     2048
#define BATCH   2
#define SEQ     1024
#define NTOK    2048
#define VOCAB   32000
#define LDSS    40   // LDS row stride in shorts (80 B, 16B-aligned, conflict-light)

typedef __attribute__((ext_vector_type(4))) float f32x4;
typedef __attribute__((ext_vector_type(2))) float f32x2;
typedef __attribute__((ext_vector_type(8))) __bf16 bf16x8;
typedef __attribute__((ext_vector_type(4))) unsigned short u16x4;

__device__ __forceinline__ unsigned short f2bf(float f) {
    union { float f; unsigned u; } v; v.f = f;
    unsigned r = v.u + 0x7FFFu + ((v.u >> 16) & 1u);
    return (unsigned short)(r >> 16);
}
__device__ __forceinline__ float bf2f(unsigned short u) {
    union { unsigned u; float f; } v; v.u = ((unsigned)u) << 16; return v.f;
}
// round-to-nearest split (one-shot staging)
__device__ __forceinline__ void split3(float x, unsigned short& h, unsigned short& m, unsigned short& l) {
    h = f2bf(x);
    float r1 = x - bf2f(h);
    m = f2bf(r1);
    float r2 = r1 - bf2f(m);
    l = f2bf(r2);
}
// trunc-based split: hi/mid exact truncation (cheap), lo rne. Residual ~2^-25.
__device__ __forceinline__ void split3t(float x, unsigned short& h, unsigned short& m, unsigned short& l) {
    union { float f; unsigned u; } a; a.f = x;
    h = (unsigned short)(a.u >> 16);
    float r1 = x - bf2f(h);          // exact
    union { float f; unsigned u; } b; b.f = r1;
    m = (unsigned short)(b.u >> 16);
    float r2 = r1 - bf2f(m);         // exact
    l = f2bf(r2);
}

#define MFMA(a, b, c) __builtin_amdgcn_mfma_f32_16x16x32_bf16((a), (b), (c), 0, 0, 0)

#define PSA ((long)NTOK * D_MODEL)       // activation plane stride
#define PSW ((long)D_MODEL * D_MODEL)    // weight plane stride

// ---------------- rmsnorm -> 3 bf16 planes ----------------
__global__ __launch_bounds__(256) void rmsnorm_kernel(const float* __restrict__ x,
    const float* __restrict__ wt, unsigned short* __restrict__ out3)
{
    __shared__ float red[4];
    int n = blockIdx.x;
    int c = threadIdx.x << 2;
    f32x4 v = *(const f32x4*)(x + (long)n*D_MODEL + c);
    float ss = v.x*v.x + v.y*v.y + v.z*v.z + v.w*v.w;
    #pragma unroll
    for (int dd = 32; dd; dd >>= 1) ss += __shfl_xor(ss, dd);
    if ((threadIdx.x & 63) == 0) red[threadIdx.x >> 6] = ss;
    __syncthreads();
    float tot = red[0] + red[1] + red[2] + red[3];
    float rms = rsqrtf(tot * (1.f / D_MODEL) + 1e-6f);
    f32x4 wv = *(const f32x4*)(wt + c);
    f32x4 o = v * rms;
    o = o * wv;
    u16x4 hv, mv, lv;
    #pragma unroll
    for (int j = 0; j < 4; j++) { unsigned short h,m,l; split3(o[j],h,m,l); hv[j]=h; mv[j]=m; lv[j]=l; }
    long idx = (long)n*D_MODEL + c;
    *(u16x4*)(out3 + 0*PSA + idx) = hv;
    *(u16x4*)(out3 + 1*PSA + idx) = mv;
    *(u16x4*)(out3 + 2*PSA + idx) = lv;
}

// ---------------- weight transpose+split: W[K][N] f32 -> out[p][N][K] bf16, 3 weights via z ----------------
__global__ __launch_bounds__(256) void wsplitT_kernel(
    const float* __restrict__ wqs, const float* __restrict__ wks, const float* __restrict__ wvs,
    unsigned short* __restrict__ oq, unsigned short* __restrict__ ok, unsigned short* __restrict__ ov)
{
    __shared__ float t[64][65];
    int k0 = blockIdx.x*64, n0 = blockIdx.y*64, z = blockIdx.z;
    const float* src = (z==0) ? wqs : (z==1) ? wks : wvs;
    unsigned short* dst = (z==0) ? oq : (z==1) ? ok : ov;
    int tid = threadIdx.x;
    int a = tid & 63, g = tid >> 6;
    #pragma unroll 4
    for (int i = 0; i < 16; i++) {
        int k = g*16 + i;
        t[k][a] = src[(long)(k0+k)*D_MODEL + n0 + a];
    }
    __syncthreads();
    #pragma unroll 4
    for (int i = 0; i < 16; i++) {
        int n = g*16 + i;
        float v = t[a][n];               // k = a
        unsigned short h,m,l; split3(v,h,m,l);
        long idx = (long)(n0+n)*D_MODEL + k0 + a;
        dst[0*PSW + idx] = h;
        dst[1*PSW + idx] = m;
        dst[2*PSW + idx] = l;
    }
}

// ---------------- QKV MULTI: A planes x W planes -> f32 out (64x64 tile, 4 blk/CU) ----------------
__global__ __launch_bounds__(256, 4) void qkv_kernel(
    const unsigned short* __restrict__ A3,
    const unsigned short* __restrict__ Wq3, const unsigned short* __restrict__ Wk3,
    const unsigned short* __restrict__ Wv3,
    float* __restrict__ qf, float* __restrict__ kf, float* __restrict__ vf)
{
    __shared__ __align__(16) unsigned short As[3][64*LDSS];
    __shared__ __align__(16) unsigned short Bs[3][64*LDSS];
    int z = blockIdx.z;
    const unsigned short* B3 = (z==0) ? Wq3 : (z==1) ? Wk3 : Wv3;
    float* out = (z==0) ? qf : (z==1) ? kf : vf;
    int n0 = blockIdx.x*64, m0 = blockIdx.y*64;
    int tid = threadIdx.x, w = tid >> 6, lane = tid & 63;
    int wm = (w >> 1)*32, wn = (w & 1)*32;
    int lr = lane & 15, lg = lane >> 4;
    f32x4 zero = {0.f,0.f,0.f,0.f};
    f32x4 acc[2][2];
    #pragma unroll
    for (int mi = 0; mi < 2; mi++)
        #pragma unroll
        for (int ni = 0; ni < 2; ni++) acc[mi][ni] = zero;
    int rb = tid >> 3, kc = (tid & 7) << 2;

    for (int k0 = 0; k0 < D_MODEL; k0 += 32) {
        #pragma unroll
        for (int p = 0; p < 2; p++) {
            int r = p*32 + rb;
            #pragma unroll
            for (int s = 0; s < 3; s++) {
                *(u16x4*)&As[s][r*LDSS + kc] = *(const u16x4*)(A3 + s*PSA + (long)(m0+r)*D_MODEL + k0 + kc);
                *(u16x4*)&Bs[s][r*LDSS + kc] = *(const u16x4*)(B3 + s*PSW + (long)(n0+r)*D_MODEL + k0 + kc);
            }
        }
        __syncthreads();
        bf16x8 bf[3][2];
        #pragma unroll
        for (int s = 0; s < 3; s++)
            #pragma unroll
            for (int ni = 0; ni < 2; ni++)
                bf[s][ni] = *(const bf16x8*)&Bs[s][(wn + ni*16 + lr)*LDSS + lg*8];
        #pragma unroll
        for (int mi = 0; mi < 2; mi++) {
            bf16x8 ah = *(const bf16x8*)&As[0][(wm + mi*16 + lr)*LDSS + lg*8];
            bf16x8 am = *(const bf16x8*)&As[1][(wm + mi*16 + lr)*LDSS + lg*8];
            bf16x8 al = *(const bf16x8*)&As[2][(wm + mi*16 + lr)*LDSS + lg*8];
            #pragma unroll
            for (int ni = 0; ni < 2; ni++) {
                acc[mi][ni] = MFMA(ah, bf[0][ni], acc[mi][ni]);
                acc[mi][ni] = MFMA(ah, bf[1][ni], acc[mi][ni]);
                acc[mi][ni] = MFMA(am, bf[0][ni], acc[mi][ni]);
                acc[mi][ni] = MFMA(ah, bf[2][ni], acc[mi][ni]);
                acc[mi][ni] = MFMA(am, bf[1][ni], acc[mi][ni]);
                acc[mi][ni] = MFMA(al, bf[0][ni], acc[mi][ni]);
            }
        }
        __syncthreads();
    }
    #pragma unroll
    for (int mi = 0; mi < 2; mi++)
        #pragma unroll
        for (int r = 0; r < 4; r++) {
            long row = m0 + wm + mi*16 + lg*4 + r;
            #pragma unroll
            for (int ni = 0; ni < 2; ni++) {
                int col = n0 + wn + ni*16 + lr;
                out[row*D_MODEL + col] = acc[mi][ni][r];
            }
        }
}

// ---------------- WO: reg-prefetch + trunc-split, h += (64x64 tile) ----------------
__global__ __launch_bounds__(256, 3) void wo_kernel(
    const float* __restrict__ A, const float* __restrict__ B, float* h)
{
    __shared__ __align__(16) unsigned short As[3][64*LDSS];
    __shared__ __align__(16) unsigned short Bs[3][64*LDSS];
    int n0 = blockIdx.x*64, m0 = blockIdx.y*64;
    int tid = threadIdx.x, w = tid >> 6, lane = tid & 63;
    int wm = (w >> 1)*32, wn = (w & 1)*32;
    int lr = lane & 15, lg = lane >> 4;
    f32x4 zero = {0.f,0.f,0.f,0.f};
    f32x4 acc[2][2];
    #pragma unroll
    for (int mi = 0; mi < 2; mi++)
        #pragma unroll
        for (int ni = 0; ni < 2; ni++) acc[mi][ni] = zero;
    int rb = tid >> 3, kc = (tid & 7) << 2;          // A staging
    int nb = (tid & 31) << 1, kb = (tid >> 5) << 2;  // B staging

    f32x4 pAv[2];
    f32x2 pBv[4];
    #pragma unroll
    for (int p = 0; p < 2; p++)
        pAv[p] = *(const f32x4*)(A + (long)(m0 + p*32 + rb)*D_MODEL + kc);
    #pragma unroll
    for (int i = 0; i < 4; i++)
        pBv[i] = *(const f32x2*)(B + (long)(kb + i)*D_MODEL + n0 + nb);

    for (int k0 = 0; k0 < D_MODEL; k0 += 32) {
        int kn = k0 + 32;
        #pragma unroll
        for (int p = 0; p < 2; p++) {
            int r = p*32 + rb;
            u16x4 hv, mv, lv;
            #pragma unroll
            for (int j = 0; j < 4; j++) { unsigned short h,m,l; split3t(pAv[p][j],h,m,l); hv[j]=h; mv[j]=m; lv[j]=l; }
            *(u16x4*)&As[0][r*LDSS + kc] = hv;
            *(u16x4*)&As[1][r*LDSS + kc] = mv;
            *(u16x4*)&As[2][r*LDSS + kc] = lv;
        }
        #pragma unroll
        for (int i = 0; i < 2; i++) {
            int r = nb + i;
            u16x4 hv, mv, lv;
            unsigned short h,m,l;
            split3t(pBv[0][i],h,m,l); hv[0]=h; mv[0]=m; lv[0]=l;
            split3t(pBv[1][i],h,m,l); hv[1]=h; mv[1]=m; lv[1]=l;
            split3t(pBv[2][i],h,m,l); hv[2]=h; mv[2]=m; lv[2]=l;
            split3t(pBv[3][i],h,m,l); hv[3]=h; mv[3]=m; lv[3]=l;
            *(u16x4*)&Bs[0][r*LDSS + kb] = hv;
            *(u16x4*)&Bs[1][r*LDSS + kb] = mv;
            *(u16x4*)&Bs[2][r*LDSS + kb] = lv;
        }
        if (kn < D_MODEL) {
            #pragma unroll
            for (int p = 0; p < 2; p++)
                pAv[p] = *(const f32x4*)(A + (long)(m0 + p*32 + rb)*D_MODEL + kn + kc);
            #pragma unroll
            for (int i = 0; i < 4; i++)
                pBv[i] = *(const f32x2*)(B + (long)(kn + kb + i)*D_MODEL + n0 + nb);
        }
        __syncthreads();
        bf16x8 bf[3][2];
        #pragma unroll
        for (int s = 0; s < 3; s++)
            #pragma unroll
            for (int ni = 0; ni < 2; ni++)
                bf[s][ni] = *(const bf16x8*)&Bs[s][(wn + ni*16 + lr)*LDSS + lg*8];
        #pragma unroll
        for (int mi = 0; mi < 2; mi++) {
            bf16x8 ah = *(const bf16x8*)&As[0][(wm + mi*16 + lr)*LDSS + lg*8];
            bf16x8 am = *(const bf16x8*)&As[1][(wm + mi*16 + lr)*LDSS + lg*8];
            bf16x8 al = *(const bf16x8*)&As[2][(wm + mi*16 + lr)*LDSS + lg*8];
            #pragma unroll
            for (int ni = 0; ni < 2; ni++) {
                acc[mi][ni] = MFMA(ah, bf[0][ni], acc[mi][ni]);
                acc[mi][ni] = MFMA(ah, bf[1][ni], acc[mi][ni]);
                acc[mi][ni] = MFMA(am, bf[0][ni], acc[mi][ni]);
                acc[mi][ni] = MFMA(ah, bf[2][ni], acc[mi][ni]);
                acc[mi][ni] = MFMA(am, bf[1][ni], acc[mi][ni]);
                acc[mi][ni] = MFMA(al, bf[0][ni], acc[mi][ni]);
            }
        }
        __syncthreads();
    }
    #pragma unroll
    for (int mi = 0; mi < 2; mi++)
        #pragma unroll
        for (int r = 0; r < 4; r++) {
            long row = m0 + wm + mi*16 + lg*4 + r;
            #pragma unroll
            for (int ni = 0; ni < 2; ni++) {
                int col = n0 + wn + ni*16 + lr;
                h[row*D_MODEL + col] += acc[mi][ni][r];
            }
        }
}

// ---------------- fused MoE w1/w3: 64x128 tile, direct staging (NO cross-MFMA prefetch regs) ----------------
template<int SPLIT>
__global__ __launch_bounds__(256, 3) void moe13_kernel(
    const unsigned short* __restrict__ A3, const float* __restrict__ W1,
    const float* __restrict__ W3, float* __restrict__ G,
    const int* __restrict__ rowidx, const int* __restrict__ counts,
    const int* __restrict__ offsets)
{
    __shared__ __align__(16) unsigned short As[SPLIT][64*LDSS];
    __shared__ __align__(16) unsigned short Bs[SPLIT][128*LDSS];
    int e = blockIdx.z;
    int cnt = counts[e], off = offsets[e];
    int n0 = blockIdx.x*128, m0 = blockIdx.y*64;
    if (m0 >= cnt) return;
    const float* b1p = W1 + (long)e * (D_MODEL*FFH);
    const float* b3p = W3 + (long)e * (D_MODEL*FFH);
    int tid = threadIdx.x, w = tid >> 6, lane = tid & 63;
    int wm = (w >> 1)*32, wn = (w & 1)*64;
    int lr = lane & 15, lg = lane >> 4;
    f32x4 zero = {0.f,0.f,0.f,0.f};
    f32x4 a1[2][4], a3[2][4];
    #pragma unroll
    for (int mi = 0; mi < 2; mi++)
        #pragma unroll
        for (int ni = 0; ni < 4; ni++) { a1[mi][ni] = zero; a3[mi][ni] = zero; }
    int rb = tid >> 3, kc = (tid & 7) << 2;

    // hoisted row gather info
    long arow[2]; int av[2];
    #pragma unroll
    for (int p = 0; p < 2; p++) {
        int r = p*32 + rb;
        av[p] = (m0 + r < cnt) ? 1 : 0;
        arow[p] = av[p] ? (long)rowidx[off + m0 + r] : 0;
    }
    u16x4 z4 = {0,0,0,0};

    for (int k0 = 0; k0 < D_MODEL; k0 += 32) {
        // stage A (direct loads)
        #pragma unroll
        for (int p = 0; p < 2; p++) {
            int r = p*32 + rb;
            #pragma unroll
            for (int s = 0; s < SPLIT; s++)
                *(u16x4*)&As[s][r*LDSS + kc] = av[p] ?
                    *(const u16x4*)(A3 + s*PSA + arow[p]*D_MODEL + k0 + kc) : z4;
        }
        // two passes: w1 then w3, direct loads in staging
        #pragma unroll
        for (int pass = 0; pass < 2; pass++) {
            const float* bp = pass ? b3p : b1p;
            f32x4 c0 = *(const f32x4*)(bp + (long)(k0+kc+0)*FFH + n0 + rb*4);
            f32x4 c1 = *(const f32x4*)(bp + (long)(k0+kc+1)*FFH + n0 + rb*4);
            f32x4 c2 = *(const f32x4*)(bp + (long)(k0+kc+2)*FFH + n0 + rb*4);
            f32x4 c3 = *(const f32x4*)(bp + (long)(k0+kc+3)*FFH + n0 + rb*4);
            #pragma unroll
            for (int i = 0; i < 4; i++) {
                int r = rb*4 + i;
                if (SPLIT == 3) {
                    u16x4 hv, mv, lv;
                    unsigned short h,m,l;
                    split3t(c0[i],h,m,l); hv[0]=h; mv[0]=m; lv[0]=l;
                    split3t(c1[i],h,m,l); hv[1]=h; mv[1]=m; lv[1]=l;
                    split3t(c2[i],h,m,l); hv[2]=h; mv[2]=m; lv[2]=l;
                    split3t(c3[i],h,m,l); hv[3]=h; mv[3]=m; lv[3]=l;
                    *(u16x4*)&Bs[0][r*LDSS + kc] = hv;
                    *(u16x4*)&Bs[1][r*LDSS + kc] = mv;
                    *(u16x4*)&Bs[2][r*LDSS + kc] = lv;
                } else {
                    u16x4 hv = {f2bf(c0[i]), f2bf(c1[i]), f2bf(c2[i]), f2bf(c3[i])};
                    *(u16x4*)&Bs[0][r*LDSS + kc] = hv;
                }
            }
            __syncthreads();
            bf16x8 bf[SPLIT][4];
            #pragma unroll
            for (int s = 0; s < SPLIT; s++)
                #pragma unroll
                for (int ni = 0; ni < 4; ni++)
                    bf[s][ni] = *(const bf16x8*)&Bs[s][(wn + ni*16 + lr)*LDSS + lg*8];
            #pragma unroll
            for (int mi = 0; mi < 2; mi++) {
                bf16x8 ah = *(const bf16x8*)&As[0][(wm + mi*16 + lr)*LDSS + lg*8];
                #pragma unroll
                for (int ni = 0; ni < 4; ni++) {
                    f32x4 a = pass ? a3[mi][ni] : a1[mi][ni];
                    a = MFMA(ah, bf[0][ni], a);
                    if (SPLIT == 3) {
                        bf16x8 am = *(const bf16x8*)&As[1][(wm + mi*16 + lr)*LDSS + lg*8];
                        bf16x8 al = *(const bf16x8*)&As[2][(wm + mi*16 + lr)*LDSS + lg*8];
                        a = MFMA(ah, bf[1][ni], a);
                        a = MFMA(am, bf[0][ni], a);
                        a = MFMA(ah, bf[2][ni], a);
                        a = MFMA(am, bf[1][ni], a);
                        a = MFMA(al, bf[0][ni], a);
                    }
                    if (pass) a3[mi][ni] = a; else a1[mi][ni] = a;
                }
            }
            __syncthreads();
        }
    }
    #pragma unroll
    for (int mi = 0; mi < 2; mi++)
        #pragma unroll
        for (int r = 0; r < 4; r++) {
            int rowl = wm + mi*16 + lg*4 + r;
            if (m0 + rowl < cnt) {
                long crow = off + m0 + rowl;
                #pragma unroll
                for (int ni = 0; ni < 4; ni++) {
                    int col = n0 + wn + ni*16 + lr;
                    float v1 = a1[mi][ni][r];
                    float v3 = a3[mi][ni][r];
                    G[crow*FFH + col] = (v1 / (1.f + expf(-v1))) * v3;
                }
            }
        }
}

// ---------------- w2: 64x64 tile, reg-prefetch + trunc-split, weighted atomic into h ----------------
template<int SPLIT>
__global__ __launch_bounds__(256, 4) void w2_kernel(
    const float* __restrict__ G, const float* __restrict__ W2, float* h,
    const int* __restrict__ rowidx, const float* __restrict__ wrow,
    const int* __restrict__ counts, const int* __restrict__ offsets)
{
    __shared__ __align__(16) unsigned short As[SPLIT][64*LDSS];
    __shared__ __align__(16) unsigned short Bs[SPLIT][64*LDSS];
    int e = blockIdx.z;
    int cnt = counts[e], off = offsets[e];
    int n0 = blockIdx.x*64, m0 = blockIdx.y*64;
    if (m0 >= cnt) return;
    const float* bp = W2 + (long)e * (FFH*D_MODEL);
    int tid = threadIdx.x, w = tid >> 6, lane = tid & 63;
    int wm = (w >> 1)*32, wn = (w & 1)*32;
    int lr = lane & 15, lg = lane >> 4;
    f32x4 zero = {0.f,0.f,0.f,0.f};
    f32x4 acc[2][2];
    #pragma unroll
    for (int mi = 0; mi < 2; mi++)
        #pragma unroll
        for (int ni = 0; ni < 2; ni++) acc[mi][ni] = zero;
    int rb = tid >> 3, kc = (tid & 7) << 2;          // A staging
    int nb = (tid & 31) << 1, kb = (tid >> 5) << 2;  // B staging

    int av[2];
    #pragma unroll
    for (int p = 0; p < 2; p++) av[p] = (m0 + p*32 + rb < cnt) ? 1 : 0;
    f32x4 pG[2];
    f32x2 pW[4];
    #pragma unroll
    for (int p = 0; p < 2; p++)
        pG[p] = av[p] ? *(const f32x4*)(G + (long)(off + m0 + p*32 + rb)*FFH + kc) : zero;
    #pragma unroll
    for (int i = 0; i < 4; i++)
        pW[i] = *(const f32x2*)(bp + (long)(kb + i)*D_MODEL + n0 + nb);

    for (int k0 = 0; k0 < FFH; k0 += 32) {
        int kn = k0 + 32;
        #pragma unroll
        for (int p = 0; p < 2; p++) {
            int r = p*32 + rb;
            if (SPLIT == 3) {
                u16x4 hv, mv, lv;
                #pragma unroll
                for (int j = 0; j < 4; j++) { unsigned short h,m,l; split3t(pG[p][j],h,m,l); hv[j]=h; mv[j]=m; lv[j]=l; }
                *(u16x4*)&As[0][r*LDSS + kc] = hv;
                *(u16x4*)&As[1][r*LDSS + kc] = mv;
                *(u16x4*)&As[2][r*LDSS + kc] = lv;
            } else {
                u16x4 hv;
                #pragma unroll
                for (int j = 0; j < 4; j++) hv[j] = f2bf(pG[p][j]);
                *(u16x4*)&As[0][r*LDSS + kc] = hv;
            }
        }
        #pragma unroll
        for (int i = 0; i < 2; i++) {
            int r = nb + i;
            if (SPLIT == 3) {
                u16x4 hv, mv, lv;
                unsigned short h,m,l;
                split3t(pW[0][i],h,m,l); hv[0]=h; mv[0]=m; lv[0]=l;
                split3t(pW[1][i],h,m,l); hv[1]=h; mv[1]=m; lv[1]=l;
                split3t(pW[2][i],h,m,l); hv[2]=h; mv[2]=m; lv[2]=l;
                split3t(pW[3][i],h,m,l); hv[3]=h; mv[3]=m; lv[3]=l;
                *(u16x4*)&Bs[0][r*LDSS + kb] = hv;
                *(u16x4*)&Bs[1][r*LDSS + kb] = mv;
                *(u16x4*)&Bs[2][r*LDSS + kb] = lv;
            } else {
                u16x4 hv = {f2bf(pW[0][i]), f2bf(pW[1][i]), f2bf(pW[2][i]), f2bf(pW[3][i])};
                *(u16x4*)&Bs[0][r*LDSS + kb] = hv;
            }
        }
        if (kn < FFH) {
            #pragma unroll
            for (int p = 0; p < 2; p++)
                pG[p] = av[p] ? *(const f32x4*)(G + (long)(off + m0 + p*32 + rb)*FFH + kn + kc) : zero;
            #pragma unroll
            for (int i = 0; i < 4; i++)
                pW[i] = *(const f32x2*)(bp + (long)(kn + kb + i)*D_MODEL + n0 + nb);
        }
        __syncthreads();
        bf16x8 bf[SPLIT][2];
        #pragma unroll
        for (int s = 0; s < SPLIT; s++)
            #pragma unroll
            for (int ni = 0; ni < 2; ni++)
                bf[s][ni] = *(const bf16x8*)&Bs[s][(wn + ni*16 + lr)*LDSS + lg*8];
        #pragma unroll
        for (int mi = 0; mi < 2; mi++) {
            bf16x8 ah = *(const bf16x8*)&As[0][(wm + mi*16 + lr)*LDSS + lg*8];
            #pragma unroll
            for (int ni = 0; ni < 2; ni++) {
                acc[mi][ni] = MFMA(ah, bf[0][ni], acc[mi][ni]);
                if (SPLIT == 3) {
                    bf16x8 am = *(const bf16x8*)&As[1][(wm + mi*16 + lr)*LDSS + lg*8];
                    bf16x8 al = *(const bf16x8*)&As[2][(wm + mi*16 + lr)*LDSS + lg*8];
                    acc[mi][ni] = MFMA(ah, bf[1][ni], acc[mi][ni]);
                    acc[mi][ni] = MFMA(am, bf[0][ni], acc[mi][ni]);
                    acc[mi][ni] = MFMA(ah, bf[2][ni], acc[mi][ni]);
                    acc[mi][ni] = MFMA(am, bf[1][ni], acc[mi][ni]);
                    acc[mi][ni] = MFMA(al, bf[0][ni], acc[mi][ni]);
                }
            }
        }
        __syncthreads();
    }
    #pragma unroll
    for (int mi = 0; mi < 2; mi++)
        #pragma unroll
        for (int r = 0; r < 4; r++) {
            int rowl = wm + mi*16 + lg*4 + r;
            if (m0 + rowl < cnt) {
                long crow = off + m0 + rowl;
                long n = rowidx[crow];
                float wgt = wrow[crow];
                #pragma unroll
                for (int ni = 0; ni < 2; ni++) {
                    int col = n0 + wn + ni*16 + lr;
                    atomicAdd(&h[n*D_MODEL + col], wgt * acc[mi][ni][r]);
                }
            }
        }
}

// ---------------- flash attention (f32 q/k/v, trunc-split inside) ----------------
__global__ __launch_bounds__(256) void attn_kernel(
    const float* __restrict__ q, const float* __restrict__ k,
    const float* __restrict__ v, float* __restrict__ att)
{
    __shared__ __align__(16) unsigned short Qs[3][64*72];
    __shared__ __align__(16) unsigned short KP[3][2560];
    __shared__ __align__(16) unsigned short Vt[3][2560];

    int qt = blockIdx.x, bh = blockIdx.y;
    int b = bh >> 4, hh = bh & 15;
    int tid = threadIdx.x, w = tid >> 6, lane = tid & 63;
    int lr = lane & 15, lg = lane >> 4;
    int lrow = tid >> 4;
    int lcol = (tid & 15) << 2;

    const float* qbase = q + ((long)(b*SEQ + qt*64) * D_MODEL + hh*64);
    #pragma unroll
    for (int p = 0; p < 4; p++) {
        int r = p*16 + lrow;
        f32x4 vv = *(const f32x4*)(qbase + (long)r * D_MODEL + lcol);
        #pragma unroll
        for (int jj = 0; jj < 4; jj++) {
            unsigned short h,m,l; split3t(vv[jj],h,m,l);
            Qs[0][r*72 + lcol + jj] = h;
            Qs[1][r*72 + lcol + jj] = m;
            Qs[2][r*72 + lcol + jj] = l;
        }
    }

    f32x4 zero = {0.f,0.f,0.f,0.f};
    f32x4 oacc[4] = {zero, zero, zero, zero};
    float mrun[4] = {-INFINITY,-INFINITY,-INFINITY,-INFINITY};
    float lrun[4] = {0.f,0.f,0.f,0.f};

    int ntile = 2*qt + 2;
    for (int jt = 0; jt < ntile; jt++) {
        const float* kbase = k + ((long)(b*SEQ + jt*32) * D_MODEL + hh*64);
        const float* vbase = v + ((long)(b*SEQ + jt*32) * D_MODEL + hh*64);
        #pragma unroll
        for (int p = 0; p < 2; p++) {
            int r = p*16 + lrow;
            f32x4 kv4 = *(const f32x4*)(kbase + (long)r * D_MODEL + lcol);
            f32x4 vv4 = *(const f32x4*)(vbase + (long)r * D_MODEL + lcol);
            #pragma unroll
            for (int jj = 0; jj < 4; jj++) {
                unsigned short h,m,l;
                split3t(kv4[jj],h,m,l);
                KP[0][r*72 + lcol + jj] = h;
                KP[1][r*72 + lcol + jj] = m;
                KP[2][r*72 + lcol + jj] = l;
                split3t(vv4[jj],h,m,l);
                Vt[0][(lcol+jj)*40 + r] = h;
                Vt[1][(lcol+jj)*40 + r] = m;
                Vt[2][(lcol+jj)*40 + r] = l;
            }
        }
        __syncthreads();

        f32x4 s[2] = {zero, zero};
        #pragma unroll
        for (int ks = 0; ks < 2; ks++) {
            bf16x8 qh = *(const bf16x8*)&Qs[0][(w*16 + lr)*72 + ks*32 + lg*8];
            bf16x8 qm = *(const bf16x8*)&Qs[1][(w*16 + lr)*72 + ks*32 + lg*8];
            bf16x8 ql = *(const bf16x8*)&Qs[2][(w*16 + lr)*72 + ks*32 + lg*8];
            #pragma unroll
            for (int ni = 0; ni < 2; ni++) {
                bf16x8 kh = *(const bf16x8*)&KP[0][(ni*16 + lr)*72 + ks*32 + lg*8];
                bf16x8 km = *(const bf16x8*)&KP[1][(ni*16 + lr)*72 + ks*32 + lg*8];
                bf16x8 kl = *(const bf16x8*)&KP[2][(ni*16 + lr)*72 + ks*32 + lg*8];
                s[ni] = MFMA(qh, kh, s[ni]);
                s[ni] = MFMA(qh, km, s[ni]);
                s[ni] = MFMA(qm, kh, s[ni]);
                s[ni] = MFMA(qh, kl, s[ni]);
                s[ni] = MFMA(qm, km, s[ni]);
                s[ni] = MFMA(ql, kh, s[ni]);
            }
        }
        __syncthreads();

        #pragma unroll
        for (int r = 0; r < 4; r++) {
            int qg = qt*64 + w*16 + lg*4 + r;
            float mx = -INFINITY;
            #pragma unroll
            for (int ni = 0; ni < 2; ni++) {
                int kg = jt*32 + ni*16 + lr;
                float val = s[ni][r] * 0.125f;
                if (kg > qg) val = -INFINITY;
                s[ni][r] = val;
                mx = fmaxf(mx, val);
            }
            #pragma unroll
            for (int dd = 1; dd < 16; dd <<= 1)
                mx = fmaxf(mx, __shfl_xor(mx, dd));
            float mnew  = fmaxf(mrun[r], mx);
            float alpha = expf(mrun[r] - mnew);
            float ps = 0.f;
            #pragma unroll
            for (int ni = 0; ni < 2; ni++) {
                float pv = expf(s[ni][r] - mnew);
                s[ni][r] = pv;
                ps += pv;
            }
            #pragma unroll
            for (int dd = 1; dd < 16; dd <<= 1)
                ps += __shfl_xor(ps, dd);
            lrun[r] = lrun[r] * alpha + ps;
            mrun[r] = mnew;
            #pragma unroll
            for (int d = 0; d < 4; d++) oacc[d][r] *= alpha;
            int prow = w*16 + lg*4 + r;
            #pragma unroll
            for (int ni = 0; ni < 2; ni++) {
                unsigned short h,m,l; split3t(s[ni][r],h,m,l);
                KP[0][prow*40 + ni*16 + lr] = h;
                KP[1][prow*40 + ni*16 + lr] = m;
                KP[2][prow*40 + ni*16 + lr] = l;
            }
        }
        {
            bf16x8 ph = *(const bf16x8*)&KP[0][(w*16 + lr)*40 + lg*8];
            bf16x8 pm = *(const bf16x8*)&KP[1][(w*16 + lr)*40 + lg*8];
            bf16x8 pl = *(const bf16x8*)&KP[2][(w*16 + lr)*40 + lg*8];
            #pragma unroll
            for (int ni = 0; ni < 4; ni++) {
                bf16x8 vh = *(const bf16x8*)&Vt[0][(ni*16 + lr)*40 + lg*8];
                bf16x8 vm = *(const bf16x8*)&Vt[1][(ni*16 + lr)*40 + lg*8];
                bf16x8 vl = *(const bf16x8*)&Vt[2][(ni*16 + lr)*40 + lg*8];
                oacc[ni] = MFMA(ph, vh, oacc[ni]);
                oacc[ni] = MFMA(ph, vm, oacc[ni]);
                oacc[ni] = MFMA(pm, vh, oacc[ni]);
                oacc[ni] = MFMA(ph, vl, oacc[ni]);
                oacc[ni] = MFMA(pm, vm, oacc[ni]);
                oacc[ni] = MFMA(pl, vh, oacc[ni]);
            }
        }
        __syncthreads();
    }
    float* obase = att + ((long)(b*SEQ + qt*64) * D_MODEL + hh*64);
    #pragma unroll
    for (int r = 0; r < 4; r++) {
        float inv = 1.f / lrun[r];
        #pragma unroll
        for (int ni = 0; ni < 4; ni++)
            obase[(long)(w*16 + lg*4 + r) * D_MODEL + ni*16 + lr] = oacc[ni][r] * inv;
    }
}

// ---------------- logits: A plane0 x B=emb (BT), f32 out ----------------
__global__ __launch_bounds__(256) void logits_kernel(
    const unsigned short* __restrict__ A0, const float* __restrict__ Bmat, float* __restrict__ C)
{
    __shared__ __align__(16) unsigned short As[128*LDSS];
    __shared__ __align__(16) unsigned short Bs[128*LDSS];
    int n0 = blockIdx.y * 128;   // vocab
    int m0 = blockIdx.x * 128;   // tokens
    int tid = threadIdx.x, w = tid >> 6, lane = tid & 63;
    int wm = (w >> 1)*64, wn = (w & 1)*64;
    int lr = lane & 15, lg = lane >> 4;
    f32x4 zero = {0.f,0.f,0.f,0.f};
    f32x4 acc[4][4];
    #pragma unroll
    for (int mi = 0; mi < 4; mi++)
        #pragma unroll
        for (int ni = 0; ni < 4; ni++) acc[mi][ni] = zero;
    int rb = tid >> 3, kc = (tid & 7) << 2;
    for (int k0 = 0; k0 < D_MODEL; k0 += 32) {
        #pragma unroll
        for (int p = 0; p < 4; p++) {
            int r = p*32 + rb;
            *(u16x4*)&As[r*LDSS + kc] = *(const u16x4*)(A0 + (long)(m0+r)*D_MODEL + k0 + kc);
            f32x4 vv = *(const f32x4*)(Bmat + (long)(n0+r)*D_MODEL + k0 + kc);
            u16x4 hv;
            #pragma unroll
            for (int j = 0; j < 4; j++) hv[j] = f2bf(vv[j]);
            *(u16x4*)&Bs[r*LDSS + kc] = hv;
        }
        __syncthreads();
        bf16x8 bfv[4], af[4];
        #pragma unroll
        for (int ni = 0; ni < 4; ni++)
            bfv[ni] = *(const bf16x8*)&Bs[(wn + ni*16 + lr)*LDSS + lg*8];
        #pragma unroll
        for (int mi = 0; mi < 4; mi++)
            af[mi] = *(const bf16x8*)&As[(wm + mi*16 + lr)*LDSS + lg*8];
        #pragma unroll
        for (int mi = 0; mi < 4; mi++)
            #pragma unroll
            for (int ni = 0; ni < 4; ni++)
                acc[mi][ni] = MFMA(af[mi], bfv[ni], acc[mi][ni]);
        __syncthreads();
    }
    #pragma unroll
    for (int mi = 0; mi < 4; mi++)
        #pragma unroll
        for (int r = 0; r < 4; r++) {
            long row = m0 + wm + mi*16 + lg*4 + r;
            #pragma unroll
            for (int ni = 0; ni < 4; ni++) {
                int col = n0 + wn + ni*16 + lr;
                C[row*VOCAB + col] = acc[mi][ni][r];
            }
        }
}

// ---------------- small kernels ----------------
__global__ __launch_bounds__(256) void embed_kernel(const int* __restrict__ tok,
    const float* __restrict__ emb, float* __restrict__ h)
{
    int n = blockIdx.x;
    int c = threadIdx.x << 2;
    long t = tok[n];
    *(f32x4*)(h + (long)n*D_MODEL + c) = *(const f32x4*)(emb + t*D_MODEL + c);
}

__global__ __launch_bounds__(256) void ropetab_kernel(float* __restrict__ tab)
{
    int idx = blockIdx.x * 256 + threadIdx.x;
    if (idx >= SEQ * 32) return;
    int t = idx >> 5, i = idx & 31;
    double inv = pow(10000.0, -(double)(2*i) / 64.0);
    double ang = (double)t * inv;
    tab[idx*2]   = (float)cos(ang);
    tab[idx*2+1] = (float)sin(ang);
}

__global__ __launch_bounds__(256) void rope_kernel(float* __restrict__ q, float* __restrict__ kk,
    const float* __restrict__ tab)
{
    int gid = blockIdx.x * 256 + threadIdx.x;
    if (gid >= NTOK * 512) return;
    int n   = gid >> 9;
    int rem = gid & 511;
    int hh  = rem >> 5;
    int i   = rem & 31;
    int t   = n & (SEQ - 1);
    float cs = tab[(t*32 + i)*2];
    float sn = tab[(t*32 + i)*2 + 1];
    long base = (long)n * D_MODEL + hh*64 + 2*i;
    float qr = q[base], qi = q[base+1];
    q[base]   = qr*cs - qi*sn;
    q[base+1] = qr*sn + qi*cs;
    float kr = kk[base], ki = kk[base+1];
    kk[base]   = kr*cs - ki*sn;
    kk[base+1] = kr*sn + ki*cs;
}

__global__ __launch_bounds__(64) void gate_kernel(const unsigned short* __restrict__ xf3,
    const float* __restrict__ gw, int* __restrict__ counts,
    int* __restrict__ eid, float* __restrict__ wts, float* __restrict__ pbuf)
{
    int n = blockIdx.x;
    int lane = threadIdx.x;
    float acc[8] = {0,0,0,0,0,0,0,0};
    for (int d0 = lane*4; d0 < D_MODEL; d0 += 256) {
        long idx = (long)n*D_MODEL + d0;
        u16x4 xh = *(const u16x4*)(xf3 + 0*PSA + idx);
        u16x4 xm = *(const u16x4*)(xf3 + 1*PSA + idx);
        u16x4 xl = *(const u16x4*)(xf3 + 2*PSA + idx);
        #pragma unroll
        for (int j = 0; j < 4; j++) {
            float xv = bf2f(xh[j]) + bf2f(xm[j]) + bf2f(xl[j]);
            const float* g = gw + (d0+j) * 8;
            #pragma unroll
            for (int e = 0; e < 8; e++) acc[e] += xv * g[e];
        }
    }
    #pragma unroll
    for (int e = 0; e < 8; e++) {
        #pragma unroll
        for (int dd = 32; dd; dd >>= 1) acc[e] += __shfl_xor(acc[e], dd);
    }
    if (lane == 0) {
        float mx = acc[0];
        #pragma unroll
        for (int e = 1; e < 8; e++) mx = fmaxf(mx, acc[e]);
        float pe[8], ssum = 0.f;
        #pragma unroll
        for (int e = 0; e < 8; e++) { pe[e] = expf(acc[e] - mx); ssum += pe[e]; }
        float sinv = 1.f / ssum;
        #pragma unroll
        for (int e = 0; e < 8; e++) { pe[e] *= sinv; pbuf[n*8 + e] = pe[e]; }
        int e1 = 0;
        #pragma unroll
        for (int e = 1; e < 8; e++) if (pe[e] > pe[e1]) e1 = e;
        int e2 = -1;
        #pragma unroll
        for (int e = 0; e < 8; e++) if (e != e1 && (e2 < 0 || pe[e] > pe[e2])) e2 = e;
        float v1 = pe[e1], v2 = pe[e2];
        float wsum = v1 + v2 + 1e-8f;
        eid[n*2] = e1; eid[n*2+1] = e2;
        wts[n*2] = v1 / wsum; wts[n*2+1] = v2 / wsum;
        atomicAdd(counts + e1, 1);
        atomicAdd(counts + e2, 1);
    }
}

__global__ __launch_bounds__(64) void scan_kernel(const int* __restrict__ counts,
    int* __restrict__ offs, int* __restrict__ cursor,
    const float* __restrict__ pbuf, float* __restrict__ aux)
{
    int t = threadIdx.x;
    int e = t & 7, c = t >> 3;
    float s = 0.f;
    for (int n = 0; n < NTOK/8; n++)
        s += pbuf[(c*(NTOK/8) + n)*8 + e];
    #pragma unroll
    for (int dd = 8; dd < 64; dd <<= 1) s += __shfl_xor(s, dd);
    __shared__ float red[8];
    if (t < 8) red[t] = s;
    __syncthreads();
    if (t == 0) {
        int o = 0; float a = 0.f;
        for (int k = 0; k < 8; k++) {
            offs[k] = o; cursor[k] = o; o += counts[k];
            a += (float)counts[k] * red[k];
        }
        aux[0] += 8.f * a / ((float)NTOK * (float)NTOK);
    }
}

__global__ __launch_bounds__(256) void assign_kernel(const int* __restrict__ eid,
    const float* __restrict__ wts, int* __restrict__ cursor,
    int* __restrict__ rowidx, float* __restrict__ wrow)
{
    int n = blockIdx.x * 256 + threadIdx.x;
    if (n >= NTOK) return;
    #pragma unroll
    for (int s = 0; s < 2; s++) {
        int e = eid[n*2 + s];
        int p = atomicAdd(cursor + e, 1);
        rowidx[p] = n;
        wrow[p] = wts[n*2 + s];
    }
}

__global__ void write_aux_kernel(float* __restrict__ out, const float* __restrict__ aux)
{
    if (threadIdx.x == 0 && blockIdx.x == 0)
        out[(long)NTOK * VOCAB] = aux[0];
}

// ---------------- launch ----------------
extern "C" void kernel_launch(void* const* d_in, const int* in_sizes, int n_in,
                              void* d_out, int out_size, void* d_ws, size_t ws_size,
                              hipStream_t stream)
{
    const int*   tokens = (const int*)d_in[0];
    const float* emb    = (const float*)d_in[1];
    const float* anw    = (const float*)d_in[2];
    const float* wq     = (const float*)d_in[3];
    const float* wk     = (const float*)d_in[4];
    const float* wv     = (const float*)d_in[5];
    const float* wo     = (const float*)d_in[6];
    const float* fnw    = (const float*)d_in[7];
    const float* gw     = (const float*)d_in[8];
    const float* w1     = (const float*)d_in[9];
    const float* w2     = (const float*)d_in[10];
    const float* w3     = (const float*)d_in[11];
    const float* finw   = (const float*)d_in[12];
    float* out = (float*)d_out;

    char* W = (char*)d_ws;
    const size_t MB = 1024u * 1024u;
    // ctrl block [0, 1MB)
    int*   counts = (int*)(W + 0);
    int*   offs   = (int*)(W + 64);
    int*   cursor = (int*)(W + 128);
    float* aux    = (float*)(W + 192);
    int*   eid    = (int*)(W + 4096);
    float* wts    = (float*)(W + 4096 + 16384);
    int*   rowix  = (int*)(W + 4096 + 32768);
    float* wrow   = (float*)(W + 4096 + 49152);
    float* pbuf   = (float*)(W + 4096 + 65536);
    float* rtab   = (float*)(W + 4096 + 131072 + 65536);
    // big buffers — lifetimes:
    //   wq3/wk3/wv3 [45,63) live wsplitT -> qkv
    //   att [45,53) live attn -> wo (weight planes dead)
    //   g [21,53) MoE phase (qkv f32 + att dead)
    // peak 63 MB
    float*          h    = (float*)(W + 1*MB);                   // [1,9)
    unsigned short* hn3  = (unsigned short*)(W + 9*MB);          // [9,21)
    float*          qf   = (float*)(W + 21*MB);                  // [21,29)
    float*          kf   = (float*)(W + 29*MB);                  // [29,37)
    float*          vf   = (float*)(W + 37*MB);                  // [37,45)
    unsigned short* wq3  = (unsigned short*)(W + 45*MB);         // [45,51)
    unsigned short* wk3  = (unsigned short*)(W + 51*MB);         // [51,57)
    unsigned short* wv3  = (unsigned short*)(W + 57*MB);         // [57,63)
    float*          att  = (float*)(W + 45*MB);                  // [45,53)
    float*          g    = (float*)(W + 21*MB);                  // [21,53) MoE phase

    hipMemsetAsync(W, 0, 256, stream);
    ropetab_kernel<<<(SEQ*32 + 255)/256, 256, 0, stream>>>(rtab);
    embed_kernel<<<NTOK, 256, 0, stream>>>(tokens, emb, h);

    for (int l = 0; l < 2; l++) {
        const float* wql = wq + (size_t)l*D_MODEL*D_MODEL;
        const float* wkl = wk + (size_t)l*D_MODEL*D_MODEL;
        const float* wvl = wv + (size_t)l*D_MODEL*D_MODEL;
        const float* wol = wo + (size_t)l*D_MODEL*D_MODEL;

        rmsnorm_kernel<<<NTOK, 256, 0, stream>>>(h, anw + (size_t)l*D_MODEL, hn3);
        wsplitT_kernel<<<dim3(16, 16, 3), 256, 0, stream>>>(wql, wkl, wvl, wq3, wk3, wv3);
        qkv_kernel<<<dim3(D_MODEL/64, NTOK/64, 3), 256, 0, stream>>>(hn3, wq3, wk3, wv3, qf, kf, vf);
        rope_kernel<<<(NTOK*512 + 255)/256, 256, 0, stream>>>(qf, kf, rtab);
        attn_kernel<<<dim3(SEQ/64, BATCH*NHEADS), 256, 0, stream>>>(qf, kf, vf, att);
        wo_kernel<<<dim3(D_MODEL/64, NTOK/64), 256, 0, stream>>>(att, wol, h);

        rmsnorm_kernel<<<NTOK, 256, 0, stream>>>(h, fnw + (size_t)l*D_MODEL, hn3);
        hipMemsetAsync(W, 0, 160, stream);   // counts/offs/cursor (aux preserved @192)
        gate_kernel<<<NTOK, 64, 0, stream>>>(hn3, gw + (size_t)l*D_MODEL*NEXP, counts, eid, wts, pbuf);
        scan_kernel<<<1, 64, 0, stream>>>(counts, offs, cursor, pbuf, aux);
        assign_kernel<<<(NTOK + 255)/256, 256, 0, stream>>>(eid, wts, cursor, rowix, wrow);

        const float* w1l = w1 + (size_t)l*NEXP*D_MODEL*FFH;
        const float* w3l = w3 + (size_t)l*NEXP*D_MODEL*FFH;
        const float* w2l = w2 + (size_t)l*NEXP*FFH*D_MODEL;
        dim3 g13(FFH/128, 2*NTOK/64, NEXP);
        dim3 g2d(D_MODEL/64, 2*NTOK/64, NEXP);
        if (l == 0) {
            moe13_kernel<3><<<g13, 256, 0, stream>>>(hn3, w1l, w3l, g, rowix, counts, offs);
            w2_kernel<3><<<g2d, 256, 0, stream>>>(g, w2l, h, rowix, wrow, counts, offs);
        } else {
            moe13_kernel<1><<<g13, 256, 0, stream>>>(hn3, w1l, w3l, g, rowix, counts, offs);
            w2_kernel<1><<<g2d, 256, 0, stream>>>(g, w2l, h, rowix, wrow, counts, offs);
        }
    }

    rmsnorm_kernel<<<NTOK, 256, 0, stream>>>(h, finw, hn3);
    logits_kernel<<<dim3(NTOK/128, VOCAB/128), 256, 0, stream>>>(hn3, emb, out);
    write_aux_kernel<<<1, 1, 0, stream>>>(out, aux);
}

// Round 10
// 1740.206 us; speedup vs baseline: 1.2050x; 1.1350x over previous
//
#include <hip/hip_runtime.h>
#include <hip/hip_bf16.h>
#include <math.h>

#define D_MODEL 1024
#define NHEADS  16
#define HDIM    64
#define NEXP    8
#define FFH     2048
#define BATCH   2
#define SEQ     1024
#define NTOK    2048
#define VOCAB   32000
#define LDSS    40   // LDS row stride in shorts (80 B, 16B-aligned, conflict-light)

typedef __attribute__((ext_vector_type(4))) float f32x4;
typedef __attribute__((ext_vector_type(2))) float f32x2;
typedef __attribute__((ext_vector_type(8))) _Float16 f16x8;
typedef __attribute__((ext_vector_type(4))) unsigned short u16x4;

// scaled fp16 2-plane split: h = fp16(64x), m = fp16((x - h/64)*2^17)
// x*y = (acc_hh + acc_cross/2048)/4096 ; residual ~2^-24 (f32-equivalent class)
#define TIER    4.8828125e-4f     // 2^-11
#define DESCALE 2.44140625e-4f    // 2^-12 = 1/S^2 (S=64)
#define INV_S   0.015625f         // 1/64
#define INV_M   7.62939453125e-6f // 1/131072

__device__ __forceinline__ unsigned short f2h(float x) {
    _Float16 h = (_Float16)x;
    union { _Float16 h; unsigned short u; } v; v.h = h; return v.u;
}
__device__ __forceinline__ float h2f(unsigned short u) {
    union { unsigned short u; _Float16 h; } v; v.u = u; return (float)v.h;
}
__device__ __forceinline__ void split2h(float x, unsigned short& h, unsigned short& m) {
    _Float16 hf = (_Float16)(x * 64.f);
    union { _Float16 h; unsigned short u; } a; a.h = hf;
    h = a.u;
    float r = x - (float)hf * INV_S;      // exact
    _Float16 mf = (_Float16)(r * 131072.f);
    union { _Float16 h; unsigned short u; } b; b.h = mf;
    m = b.u;
}

#define MFMAH(a, b, c) __builtin_amdgcn_mfma_f32_16x16x32_f16((a), (b), (c), 0, 0, 0)

#define PSA ((long)NTOK * D_MODEL)       // activation plane stride
#define PSW ((long)D_MODEL * D_MODEL)    // weight plane stride

// ---------------- rmsnorm -> 2 fp16 planes (scaled) ----------------
__global__ __launch_bounds__(256) void rmsnorm_kernel(const float* __restrict__ x,
    const float* __restrict__ wt, unsigned short* __restrict__ out2)
{
    __shared__ float red[4];
    int n = blockIdx.x;
    int c = threadIdx.x << 2;
    f32x4 v = *(const f32x4*)(x + (long)n*D_MODEL + c);
    float ss = v.x*v.x + v.y*v.y + v.z*v.z + v.w*v.w;
    #pragma unroll
    for (int dd = 32; dd; dd >>= 1) ss += __shfl_xor(ss, dd);
    if ((threadIdx.x & 63) == 0) red[threadIdx.x >> 6] = ss;
    __syncthreads();
    float tot = red[0] + red[1] + red[2] + red[3];
    float rms = rsqrtf(tot * (1.f / D_MODEL) + 1e-6f);
    f32x4 wv = *(const f32x4*)(wt + c);
    f32x4 o = v * rms;
    o = o * wv;
    u16x4 hv, mv;
    #pragma unroll
    for (int j = 0; j < 4; j++) { unsigned short h,m; split2h(o[j],h,m); hv[j]=h; mv[j]=m; }
    long idx = (long)n*D_MODEL + c;
    *(u16x4*)(out2 + 0*PSA + idx) = hv;
    *(u16x4*)(out2 + 1*PSA + idx) = mv;
}

// ---------------- weight transpose+split: W[K][N] f32 -> out[p][N][K] fp16x2, z picks weight ----------------
__global__ __launch_bounds__(256) void wsplitT_kernel(
    const float* __restrict__ wqs, const float* __restrict__ wks, const float* __restrict__ wvs,
    unsigned short* __restrict__ oq, unsigned short* __restrict__ ok, unsigned short* __restrict__ ov)
{
    __shared__ float t[64][65];
    int k0 = blockIdx.x*64, n0 = blockIdx.y*64, z = blockIdx.z;
    const float* src = (z==0) ? wqs : (z==1) ? wks : wvs;
    unsigned short* dst = (z==0) ? oq : (z==1) ? ok : ov;
    int tid = threadIdx.x;
    int a = tid & 63, g = tid >> 6;
    #pragma unroll 4
    for (int i = 0; i < 16; i++) {
        int k = g*16 + i;
        t[k][a] = src[(long)(k0+k)*D_MODEL + n0 + a];
    }
    __syncthreads();
    #pragma unroll 4
    for (int i = 0; i < 16; i++) {
        int n = g*16 + i;
        float v = t[a][n];               // k = a
        unsigned short h,m; split2h(v,h,m);
        long idx = (long)(n0+n)*D_MODEL + k0 + a;
        dst[0*PSW + idx] = h;
        dst[1*PSW + idx] = m;
    }
}

// ---------------- QKV MULTI: A planes x W planes -> f32 out (64x64 tile) ----------------
__global__ __launch_bounds__(256, 4) void qkv_kernel(
    const unsigned short* __restrict__ A2,
    const unsigned short* __restrict__ Wq2, const unsigned short* __restrict__ Wk2,
    const unsigned short* __restrict__ Wv2,
    float* __restrict__ qf, float* __restrict__ kf, float* __restrict__ vf)
{
    __shared__ __align__(16) unsigned short As[2][64*LDSS];
    __shared__ __align__(16) unsigned short Bs[2][64*LDSS];
    int z = blockIdx.z;
    const unsigned short* B2 = (z==0) ? Wq2 : (z==1) ? Wk2 : Wv2;
    float* out = (z==0) ? qf : (z==1) ? kf : vf;
    int n0 = blockIdx.x*64, m0 = blockIdx.y*64;
    int tid = threadIdx.x, w = tid >> 6, lane = tid & 63;
    int wm = (w >> 1)*32, wn = (w & 1)*32;
    int lr = lane & 15, lg = lane >> 4;
    f32x4 zero = {0.f,0.f,0.f,0.f};
    f32x4 a0[2][2], a1[2][2];
    #pragma unroll
    for (int mi = 0; mi < 2; mi++)
        #pragma unroll
        for (int ni = 0; ni < 2; ni++) { a0[mi][ni] = zero; a1[mi][ni] = zero; }
    int rb = tid >> 3, kc = (tid & 7) << 2;

    for (int k0 = 0; k0 < D_MODEL; k0 += 32) {
        #pragma unroll
        for (int p = 0; p < 2; p++) {
            int r = p*32 + rb;
            #pragma unroll
            for (int s = 0; s < 2; s++) {
                *(u16x4*)&As[s][r*LDSS + kc] = *(const u16x4*)(A2 + s*PSA + (long)(m0+r)*D_MODEL + k0 + kc);
                *(u16x4*)&Bs[s][r*LDSS + kc] = *(const u16x4*)(B2 + s*PSW + (long)(n0+r)*D_MODEL + k0 + kc);
            }
        }
        __syncthreads();
        f16x8 bh[2], bm[2];
        #pragma unroll
        for (int ni = 0; ni < 2; ni++) {
            bh[ni] = *(const f16x8*)&Bs[0][(wn + ni*16 + lr)*LDSS + lg*8];
            bm[ni] = *(const f16x8*)&Bs[1][(wn + ni*16 + lr)*LDSS + lg*8];
        }
        #pragma unroll
        for (int mi = 0; mi < 2; mi++) {
            f16x8 ah = *(const f16x8*)&As[0][(wm + mi*16 + lr)*LDSS + lg*8];
            f16x8 am = *(const f16x8*)&As[1][(wm + mi*16 + lr)*LDSS + lg*8];
            #pragma unroll
            for (int ni = 0; ni < 2; ni++) {
                a0[mi][ni] = MFMAH(ah, bh[ni], a0[mi][ni]);
                a1[mi][ni] = MFMAH(ah, bm[ni], a1[mi][ni]);
                a1[mi][ni] = MFMAH(am, bh[ni], a1[mi][ni]);
            }
        }
        __syncthreads();
    }
    #pragma unroll
    for (int mi = 0; mi < 2; mi++)
        #pragma unroll
        for (int r = 0; r < 4; r++) {
            long row = m0 + wm + mi*16 + lg*4 + r;
            #pragma unroll
            for (int ni = 0; ni < 2; ni++) {
                int col = n0 + wn + ni*16 + lr;
                out[row*D_MODEL + col] = (a0[mi][ni][r] + a1[mi][ni][r]*TIER) * DESCALE;
            }
        }
}

// ---------------- WO: reg-prefetch + fp16-2 split, h += (64x64 tile) ----------------
__global__ __launch_bounds__(256, 3) void wo_kernel(
    const float* __restrict__ A, const float* __restrict__ B, float* h)
{
    __shared__ __align__(16) unsigned short As[2][64*LDSS];
    __shared__ __align__(16) unsigned short Bs[2][64*LDSS];
    int n0 = blockIdx.x*64, m0 = blockIdx.y*64;
    int tid = threadIdx.x, w = tid >> 6, lane = tid & 63;
    int wm = (w >> 1)*32, wn = (w & 1)*32;
    int lr = lane & 15, lg = lane >> 4;
    f32x4 zero = {0.f,0.f,0.f,0.f};
    f32x4 a0[2][2], a1[2][2];
    #pragma unroll
    for (int mi = 0; mi < 2; mi++)
        #pragma unroll
        for (int ni = 0; ni < 2; ni++) { a0[mi][ni] = zero; a1[mi][ni] = zero; }
    int rb = tid >> 3, kc = (tid & 7) << 2;          // A staging
    int nb = (tid & 31) << 1, kb = (tid >> 5) << 2;  // B staging

    f32x4 pAv[2];
    f32x2 pBv[4];
    #pragma unroll
    for (int p = 0; p < 2; p++)
        pAv[p] = *(const f32x4*)(A + (long)(m0 + p*32 + rb)*D_MODEL + kc);
    #pragma unroll
    for (int i = 0; i < 4; i++)
        pBv[i] = *(const f32x2*)(B + (long)(kb + i)*D_MODEL + n0 + nb);

    for (int k0 = 0; k0 < D_MODEL; k0 += 32) {
        int kn = k0 + 32;
        #pragma unroll
        for (int p = 0; p < 2; p++) {
            int r = p*32 + rb;
            u16x4 hv, mv;
            #pragma unroll
            for (int j = 0; j < 4; j++) { unsigned short hh,mm; split2h(pAv[p][j],hh,mm); hv[j]=hh; mv[j]=mm; }
            *(u16x4*)&As[0][r*LDSS + kc] = hv;
            *(u16x4*)&As[1][r*LDSS + kc] = mv;
        }
        #pragma unroll
        for (int i = 0; i < 2; i++) {
            int r = nb + i;
            u16x4 hv, mv;
            unsigned short hh,mm;
            split2h(pBv[0][i],hh,mm); hv[0]=hh; mv[0]=mm;
            split2h(pBv[1][i],hh,mm); hv[1]=hh; mv[1]=mm;
            split2h(pBv[2][i],hh,mm); hv[2]=hh; mv[2]=mm;
            split2h(pBv[3][i],hh,mm); hv[3]=hh; mv[3]=mm;
            *(u16x4*)&Bs[0][r*LDSS + kb] = hv;
            *(u16x4*)&Bs[1][r*LDSS + kb] = mv;
        }
        if (kn < D_MODEL) {
            #pragma unroll
            for (int p = 0; p < 2; p++)
                pAv[p] = *(const f32x4*)(A + (long)(m0 + p*32 + rb)*D_MODEL + kn + kc);
            #pragma unroll
            for (int i = 0; i < 4; i++)
                pBv[i] = *(const f32x2*)(B + (long)(kn + kb + i)*D_MODEL + n0 + nb);
        }
        __syncthreads();
        f16x8 bh[2], bm[2];
        #pragma unroll
        for (int ni = 0; ni < 2; ni++) {
            bh[ni] = *(const f16x8*)&Bs[0][(wn + ni*16 + lr)*LDSS + lg*8];
            bm[ni] = *(const f16x8*)&Bs[1][(wn + ni*16 + lr)*LDSS + lg*8];
        }
        #pragma unroll
        for (int mi = 0; mi < 2; mi++) {
            f16x8 ah = *(const f16x8*)&As[0][(wm + mi*16 + lr)*LDSS + lg*8];
            f16x8 am = *(const f16x8*)&As[1][(wm + mi*16 + lr)*LDSS + lg*8];
            #pragma unroll
            for (int ni = 0; ni < 2; ni++) {
                a0[mi][ni] = MFMAH(ah, bh[ni], a0[mi][ni]);
                a1[mi][ni] = MFMAH(ah, bm[ni], a1[mi][ni]);
                a1[mi][ni] = MFMAH(am, bh[ni], a1[mi][ni]);
            }
        }
        __syncthreads();
    }
    #pragma unroll
    for (int mi = 0; mi < 2; mi++)
        #pragma unroll
        for (int r = 0; r < 4; r++) {
            long row = m0 + wm + mi*16 + lg*4 + r;
            #pragma unroll
            for (int ni = 0; ni < 2; ni++) {
                int col = n0 + wn + ni*16 + lr;
                h[row*D_MODEL + col] += (a0[mi][ni][r] + a1[mi][ni][r]*TIER) * DESCALE;
            }
        }
}

// ---------------- fused MoE w1/w3: 64x128 tile, two k-loops (w1 then w3) ----------------
// SPL=2: fp16 dual-plane (f32-accurate). SPL=1: single fp16 h-plane (A scaled, epi /64).
template<int SPL>
__global__ __launch_bounds__(256, 3) void moe13_kernel(
    const unsigned short* __restrict__ A2, const float* __restrict__ W1,
    const float* __restrict__ W3, float* __restrict__ G,
    const int* __restrict__ rowidx, const int* __restrict__ counts,
    const int* __restrict__ offsets)
{
    __shared__ __align__(16) unsigned short As[SPL][64*LDSS];
    __shared__ __align__(16) unsigned short Bs[SPL][128*LDSS];
    const int P1 = (SPL == 2) ? 1 : 0;
    int e = blockIdx.z;
    int cnt = counts[e], off = offsets[e];
    int n0 = blockIdx.x*128, m0 = blockIdx.y*64;
    if (m0 >= cnt) return;
    int tid = threadIdx.x, w = tid >> 6, lane = tid & 63;
    int wm = (w >> 1)*32, wn = (w & 1)*64;
    int lr = lane & 15, lg = lane >> 4;
    int rb = tid >> 3, kc = (tid & 7) << 2;
    f32x4 zero = {0.f,0.f,0.f,0.f};

    long arow[2]; int av[2];
    #pragma unroll
    for (int p = 0; p < 2; p++) {
        int r = p*32 + rb;
        av[p] = (m0 + r < cnt) ? 1 : 0;
        arow[p] = av[p] ? (long)rowidx[off + m0 + r] : 0;
    }
    u16x4 z4 = {0,0,0,0};
    f32x4 sl[2][4];   // silu(w1 result) kept in regs between loops

    #pragma unroll
    for (int mat = 0; mat < 2; mat++) {
        const float* bp = (mat ? W3 : W1) + (long)e * (D_MODEL*FFH);
        f32x4 a0[2][4], a1t[2][4];
        #pragma unroll
        for (int mi = 0; mi < 2; mi++)
            #pragma unroll
            for (int ni = 0; ni < 4; ni++) { a0[mi][ni] = zero; a1t[mi][ni] = zero; }

        for (int k0 = 0; k0 < D_MODEL; k0 += 32) {
            // stage A (pure copies from planes)
            #pragma unroll
            for (int p = 0; p < 2; p++) {
                int r = p*32 + rb;
                #pragma unroll
                for (int s = 0; s < SPL; s++)
                    *(u16x4*)&As[s][r*LDSS + kc] = av[p] ?
                        *(const u16x4*)(A2 + s*PSA + arow[p]*D_MODEL + k0 + kc) : z4;
            }
            // stage B
            f32x4 c0 = *(const f32x4*)(bp + (long)(k0+kc+0)*FFH + n0 + rb*4);
            f32x4 c1 = *(const f32x4*)(bp + (long)(k0+kc+1)*FFH + n0 + rb*4);
            f32x4 c2 = *(const f32x4*)(bp + (long)(k0+kc+2)*FFH + n0 + rb*4);
            f32x4 c3 = *(const f32x4*)(bp + (long)(k0+kc+3)*FFH + n0 + rb*4);
            #pragma unroll
            for (int i = 0; i < 4; i++) {
                int r = rb*4 + i;
                if (SPL == 2) {
                    u16x4 hv, mv;
                    unsigned short hh,mm;
                    split2h(c0[i],hh,mm); hv[0]=hh; mv[0]=mm;
                    split2h(c1[i],hh,mm); hv[1]=hh; mv[1]=mm;
                    split2h(c2[i],hh,mm); hv[2]=hh; mv[2]=mm;
                    split2h(c3[i],hh,mm); hv[3]=hh; mv[3]=mm;
                    *(u16x4*)&Bs[0][r*LDSS + kc] = hv;
                    *(u16x4*)&Bs[P1][r*LDSS + kc] = mv;
                } else {
                    u16x4 hv = {f2h(c0[i]), f2h(c1[i]), f2h(c2[i]), f2h(c3[i])};
                    *(u16x4*)&Bs[0][r*LDSS + kc] = hv;
                }
            }
            __syncthreads();
            f16x8 bh[4], bm[4];
            #pragma unroll
            for (int ni = 0; ni < 4; ni++) {
                bh[ni] = *(const f16x8*)&Bs[0][(wn + ni*16 + lr)*LDSS + lg*8];
                if (SPL == 2) bm[ni] = *(const f16x8*)&Bs[P1][(wn + ni*16 + lr)*LDSS + lg*8];
            }
            #pragma unroll
            for (int mi = 0; mi < 2; mi++) {
                f16x8 ah = *(const f16x8*)&As[0][(wm + mi*16 + lr)*LDSS + lg*8];
                #pragma unroll
                for (int ni = 0; ni < 4; ni++) {
                    a0[mi][ni] = MFMAH(ah, bh[ni], a0[mi][ni]);
                    if (SPL == 2) {
                        f16x8 am = *(const f16x8*)&As[P1][(wm + mi*16 + lr)*LDSS + lg*8];
                        a1t[mi][ni] = MFMAH(ah, bm[ni], a1t[mi][ni]);
                        a1t[mi][ni] = MFMAH(am, bh[ni], a1t[mi][ni]);
                    }
                }
            }
            __syncthreads();
        }
        // combine tiers
        if (mat == 0) {
            #pragma unroll
            for (int mi = 0; mi < 2; mi++)
                #pragma unroll
                for (int ni = 0; ni < 4; ni++) {
                    f32x4 v = (SPL == 2) ? (a0[mi][ni] + a1t[mi][ni]*TIER)*DESCALE
                                         : a0[mi][ni]*INV_S;
                    #pragma unroll
                    for (int r = 0; r < 4; r++) {
                        float s = v[r];
                        v[r] = s / (1.f + expf(-s));
                    }
                    sl[mi][ni] = v;
                }
        } else {
            #pragma unroll
            for (int mi = 0; mi < 2; mi++)
                #pragma unroll
                for (int r = 0; r < 4; r++) {
                    int rowl = wm + mi*16 + lg*4 + r;
                    if (m0 + rowl < cnt) {
                        long crow = off + m0 + rowl;
                        #pragma unroll
                        for (int ni = 0; ni < 4; ni++) {
                            int col = n0 + wn + ni*16 + lr;
                            float v3 = (SPL == 2) ? (a0[mi][ni][r] + a1t[mi][ni][r]*TIER)*DESCALE
                                                  : a0[mi][ni][r]*INV_S;
                            G[crow*FFH + col] = sl[mi][ni][r] * v3;
                        }
                    }
                }
        }
    }
}

// ---------------- w2: 64x64 tile, reg-prefetch + fp16-2 split, weighted atomic into h ----------------
template<int SPL>
__global__ __launch_bounds__(256, 4) void w2_kernel(
    const float* __restrict__ G, const float* __restrict__ W2, float* h,
    const int* __restrict__ rowidx, const float* __restrict__ wrow,
    const int* __restrict__ counts, const int* __restrict__ offsets)
{
    __shared__ __align__(16) unsigned short As[SPL][64*LDSS];
    __shared__ __align__(16) unsigned short Bs[SPL][64*LDSS];
    const int P1 = (SPL == 2) ? 1 : 0;
    int e = blockIdx.z;
    int cnt = counts[e], off = offsets[e];
    int n0 = blockIdx.x*64, m0 = blockIdx.y*64;
    if (m0 >= cnt) return;
    const float* bp = W2 + (long)e * (FFH*D_MODEL);
    int tid = threadIdx.x, w = tid >> 6, lane = tid & 63;
    int wm = (w >> 1)*32, wn = (w & 1)*32;
    int lr = lane & 15, lg = lane >> 4;
    f32x4 zero = {0.f,0.f,0.f,0.f};
    f32x4 a0[2][2], a1[2][2];
    #pragma unroll
    for (int mi = 0; mi < 2; mi++)
        #pragma unroll
        for (int ni = 0; ni < 2; ni++) { a0[mi][ni] = zero; a1[mi][ni] = zero; }
    int rb = tid >> 3, kc = (tid & 7) << 2;          // A staging
    int nb = (tid & 31) << 1, kb = (tid >> 5) << 2;  // B staging

    int av[2];
    #pragma unroll
    for (int p = 0; p < 2; p++) av[p] = (m0 + p*32 + rb < cnt) ? 1 : 0;
    f32x4 pG[2];
    f32x2 pW[4];
    #pragma unroll
    for (int p = 0; p < 2; p++)
        pG[p] = av[p] ? *(const f32x4*)(G + (long)(off + m0 + p*32 + rb)*FFH + kc) : zero;
    #pragma unroll
    for (int i = 0; i < 4; i++)
        pW[i] = *(const f32x2*)(bp + (long)(kb + i)*D_MODEL + n0 + nb);

    for (int k0 = 0; k0 < FFH; k0 += 32) {
        int kn = k0 + 32;
        #pragma unroll
        for (int p = 0; p < 2; p++) {
            int r = p*32 + rb;
            if (SPL == 2) {
                u16x4 hv, mv;
                #pragma unroll
                for (int j = 0; j < 4; j++) { unsigned short hh,mm; split2h(pG[p][j],hh,mm); hv[j]=hh; mv[j]=mm; }
                *(u16x4*)&As[0][r*LDSS + kc] = hv;
                *(u16x4*)&As[P1][r*LDSS + kc] = mv;
            } else {
                u16x4 hv;
                #pragma unroll
                for (int j = 0; j < 4; j++) hv[j] = f2h(pG[p][j]);
                *(u16x4*)&As[0][r*LDSS + kc] = hv;
            }
        }
        #pragma unroll
        for (int i = 0; i < 2; i++) {
            int r = nb + i;
            if (SPL == 2) {
                u16x4 hv, mv;
                unsigned short hh,mm;
                split2h(pW[0][i],hh,mm); hv[0]=hh; mv[0]=mm;
                split2h(pW[1][i],hh,mm); hv[1]=hh; mv[1]=mm;
                split2h(pW[2][i],hh,mm); hv[2]=hh; mv[2]=mm;
                split2h(pW[3][i],hh,mm); hv[3]=hh; mv[3]=mm;
                *(u16x4*)&Bs[0][r*LDSS + kb] = hv;
                *(u16x4*)&Bs[P1][r*LDSS + kb] = mv;
            } else {
                u16x4 hv = {f2h(pW[0][i]), f2h(pW[1][i]), f2h(pW[2][i]), f2h(pW[3][i])};
                *(u16x4*)&Bs[0][r*LDSS + kb] = hv;
            }
        }
        if (kn < FFH) {
            #pragma unroll
            for (int p = 0; p < 2; p++)
                pG[p] = av[p] ? *(const f32x4*)(G + (long)(off + m0 + p*32 + rb)*FFH + kn + kc) : zero;
            #pragma unroll
            for (int i = 0; i < 4; i++)
                pW[i] = *(const f32x2*)(bp + (long)(kn + kb + i)*D_MODEL + n0 + nb);
        }
        __syncthreads();
        f16x8 bh[2], bm[2];
        #pragma unroll
        for (int ni = 0; ni < 2; ni++) {
            bh[ni] = *(const f16x8*)&Bs[0][(wn + ni*16 + lr)*LDSS + lg*8];
            if (SPL == 2) bm[ni] = *(const f16x8*)&Bs[P1][(wn + ni*16 + lr)*LDSS + lg*8];
        }
        #pragma unroll
        for (int mi = 0; mi < 2; mi++) {
            f16x8 ah = *(const f16x8*)&As[0][(wm + mi*16 + lr)*LDSS + lg*8];
            #pragma unroll
            for (int ni = 0; ni < 2; ni++) {
                a0[mi][ni] = MFMAH(ah, bh[ni], a0[mi][ni]);
                if (SPL == 2) {
                    f16x8 am = *(const f16x8*)&As[P1][(wm + mi*16 + lr)*LDSS + lg*8];
                    a1[mi][ni] = MFMAH(ah, bm[ni], a1[mi][ni]);
                    a1[mi][ni] = MFMAH(am, bh[ni], a1[mi][ni]);
                }
            }
        }
        __syncthreads();
    }
    #pragma unroll
    for (int mi = 0; mi < 2; mi++)
        #pragma unroll
        for (int r = 0; r < 4; r++) {
            int rowl = wm + mi*16 + lg*4 + r;
            if (m0 + rowl < cnt) {
                long crow = off + m0 + rowl;
                long n = rowidx[crow];
                float wgt = wrow[crow];
                #pragma unroll
                for (int ni = 0; ni < 2; ni++) {
                    int col = n0 + wn + ni*16 + lr;
                    float val = (SPL == 2) ? (a0[mi][ni][r] + a1[mi][ni][r]*TIER)*DESCALE
                                           : a0[mi][ni][r];
                    atomicAdd(&h[n*D_MODEL + col], wgt * val);
                }
            }
        }
}

// ---------------- flash attention (f32 q/k/v, fp16-2 split inside) ----------------
__global__ __launch_bounds__(256, 3) void attn_kernel(
    const float* __restrict__ q, const float* __restrict__ k,
    const float* __restrict__ v, float* __restrict__ att)
{
    __shared__ __align__(16) unsigned short Qs[2][64*72];
    __shared__ __align__(16) unsigned short KP[2][2560];
    __shared__ __align__(16) unsigned short Vt[2][2560];

    int qt = blockIdx.x, bh = blockIdx.y;
    int b = bh >> 4, hh = bh & 15;
    int tid = threadIdx.x, w = tid >> 6, lane = tid & 63;
    int lr = lane & 15, lg = lane >> 4;
    int lrow = tid >> 4;
    int lcol = (tid & 15) << 2;

    const float* qbase = q + ((long)(b*SEQ + qt*64) * D_MODEL + hh*64);
    #pragma unroll
    for (int p = 0; p < 4; p++) {
        int r = p*16 + lrow;
        f32x4 vv = *(const f32x4*)(qbase + (long)r * D_MODEL + lcol);
        #pragma unroll
        for (int jj = 0; jj < 4; jj++) {
            unsigned short hh2,mm2; split2h(vv[jj],hh2,mm2);
            Qs[0][r*72 + lcol + jj] = hh2;
            Qs[1][r*72 + lcol + jj] = mm2;
        }
    }

    f32x4 zero = {0.f,0.f,0.f,0.f};
    f32x4 o0[4] = {zero, zero, zero, zero};
    f32x4 o1[4] = {zero, zero, zero, zero};
    float mrun[4] = {-INFINITY,-INFINITY,-INFINITY,-INFINITY};
    float lrun[4] = {0.f,0.f,0.f,0.f};

    int ntile = 2*qt + 2;
    for (int jt = 0; jt < ntile; jt++) {
        const float* kbase = k + ((long)(b*SEQ + jt*32) * D_MODEL + hh*64);
        const float* vbase = v + ((long)(b*SEQ + jt*32) * D_MODEL + hh*64);
        #pragma unroll
        for (int p = 0; p < 2; p++) {
            int r = p*16 + lrow;
            f32x4 kv4 = *(const f32x4*)(kbase + (long)r * D_MODEL + lcol);
            f32x4 vv4 = *(const f32x4*)(vbase + (long)r * D_MODEL + lcol);
            #pragma unroll
            for (int jj = 0; jj < 4; jj++) {
                unsigned short hh2,mm2;
                split2h(kv4[jj],hh2,mm2);
                KP[0][r*72 + lcol + jj] = hh2;
                KP[1][r*72 + lcol + jj] = mm2;
                split2h(vv4[jj],hh2,mm2);
                Vt[0][(lcol+jj)*40 + r] = hh2;
                Vt[1][(lcol+jj)*40 + r] = mm2;
            }
        }
        __syncthreads();

        f32x4 s0[2] = {zero, zero};
        f32x4 s1[2] = {zero, zero};
        #pragma unroll
        for (int ks = 0; ks < 2; ks++) {
            f16x8 qh = *(const f16x8*)&Qs[0][(w*16 + lr)*72 + ks*32 + lg*8];
            f16x8 qm = *(const f16x8*)&Qs[1][(w*16 + lr)*72 + ks*32 + lg*8];
            #pragma unroll
            for (int ni = 0; ni < 2; ni++) {
                f16x8 kh = *(const f16x8*)&KP[0][(ni*16 + lr)*72 + ks*32 + lg*8];
                f16x8 km = *(const f16x8*)&KP[1][(ni*16 + lr)*72 + ks*32 + lg*8];
                s0[ni] = MFMAH(qh, kh, s0[ni]);
                s1[ni] = MFMAH(qh, km, s1[ni]);
                s1[ni] = MFMAH(qm, kh, s1[ni]);
            }
        }
        __syncthreads();

        #pragma unroll
        for (int r = 0; r < 4; r++) {
            int qg = qt*64 + w*16 + lg*4 + r;
            float sv[2];
            float mx = -INFINITY;
            #pragma unroll
            for (int ni = 0; ni < 2; ni++) {
                int kg = jt*32 + ni*16 + lr;
                float val = (s0[ni][r] + s1[ni][r]*TIER) * (0.125f * DESCALE);
                if (kg > qg) val = -INFINITY;
                sv[ni] = val;
                mx = fmaxf(mx, val);
            }
            #pragma unroll
            for (int dd = 1; dd < 16; dd <<= 1)
                mx = fmaxf(mx, __shfl_xor(mx, dd));
            float mnew  = fmaxf(mrun[r], mx);
            float alpha = expf(mrun[r] - mnew);
            float ps = 0.f;
            #pragma unroll
            for (int ni = 0; ni < 2; ni++) {
                float pv = expf(sv[ni] - mnew);
                sv[ni] = pv;
                ps += pv;
            }
            #pragma unroll
            for (int dd = 1; dd < 16; dd <<= 1)
                ps += __shfl_xor(ps, dd);
            lrun[r] = lrun[r] * alpha + ps;
            mrun[r] = mnew;
            #pragma unroll
            for (int d = 0; d < 4; d++) { o0[d][r] *= alpha; o1[d][r] *= alpha; }
            int prow = w*16 + lg*4 + r;
            #pragma unroll
            for (int ni = 0; ni < 2; ni++) {
                unsigned short hh2,mm2; split2h(sv[ni],hh2,mm2);
                KP[0][prow*40 + ni*16 + lr] = hh2;
                KP[1][prow*40 + ni*16 + lr] = mm2;
            }
        }
        {
            f16x8 ph = *(const f16x8*)&KP[0][(w*16 + lr)*40 + lg*8];
            f16x8 pm = *(const f16x8*)&KP[1][(w*16 + lr)*40 + lg*8];
            #pragma unroll
            for (int ni = 0; ni < 4; ni++) {
                f16x8 vh = *(const f16x8*)&Vt[0][(ni*16 + lr)*40 + lg*8];
                f16x8 vm = *(const f16x8*)&Vt[1][(ni*16 + lr)*40 + lg*8];
                o0[ni] = MFMAH(ph, vh, o0[ni]);
                o1[ni] = MFMAH(ph, vm, o1[ni]);
                o1[ni] = MFMAH(pm, vh, o1[ni]);
            }
        }
        __syncthreads();
    }
    float* obase = att + ((long)(b*SEQ + qt*64) * D_MODEL + hh*64);
    #pragma unroll
    for (int r = 0; r < 4; r++) {
        float inv = DESCALE / lrun[r];
        #pragma unroll
        for (int ni = 0; ni < 4; ni++)
            obase[(long)(w*16 + lg*4 + r) * D_MODEL + ni*16 + lr] =
                (o0[ni][r] + o1[ni][r]*TIER) * inv;
    }
}

// ---------------- logits: A = fp16 h-plane (scaled x64) x B = f2h(emb), f32 out /64 ----------------
__global__ __launch_bounds__(256) void logits_kernel(
    const unsigned short* __restrict__ A0, const float* __restrict__ Bmat, float* __restrict__ C)
{
    __shared__ __align__(16) unsigned short As[128*LDSS];
    __shared__ __align__(16) unsigned short Bs[128*LDSS];
    int n0 = blockIdx.y * 128;   // vocab
    int m0 = blockIdx.x * 128;   // tokens
    int tid = threadIdx.x, w = tid >> 6, lane = tid & 63;
    int wm = (w >> 1)*64, wn = (w & 1)*64;
    int lr = lane & 15, lg = lane >> 4;
    f32x4 zero = {0.f,0.f,0.f,0.f};
    f32x4 acc[4][4];
    #pragma unroll
    for (int mi = 0; mi < 4; mi++)
        #pragma unroll
        for (int ni = 0; ni < 4; ni++) acc[mi][ni] = zero;
    int rb = tid >> 3, kc = (tid & 7) << 2;
    for (int k0 = 0; k0 < D_MODEL; k0 += 32) {
        #pragma unroll
        for (int p = 0; p < 4; p++) {
            int r = p*32 + rb;
            *(u16x4*)&As[r*LDSS + kc] = *(const u16x4*)(A0 + (long)(m0+r)*D_MODEL + k0 + kc);
            f32x4 vv = *(const f32x4*)(Bmat + (long)(n0+r)*D_MODEL + k0 + kc);
            u16x4 hv;
            #pragma unroll
            for (int j = 0; j < 4; j++) hv[j] = f2h(vv[j]);
            *(u16x4*)&Bs[r*LDSS + kc] = hv;
        }
        __syncthreads();
        f16x8 bfv[4], af[4];
        #pragma unroll
        for (int ni = 0; ni < 4; ni++)
            bfv[ni] = *(const f16x8*)&Bs[(wn + ni*16 + lr)*LDSS + lg*8];
        #pragma unroll
        for (int mi = 0; mi < 4; mi++)
            af[mi] = *(const f16x8*)&As[(wm + mi*16 + lr)*LDSS + lg*8];
        #pragma unroll
        for (int mi = 0; mi < 4; mi++)
            #pragma unroll
            for (int ni = 0; ni < 4; ni++)
                acc[mi][ni] = MFMAH(af[mi], bfv[ni], acc[mi][ni]);
        __syncthreads();
    }
    #pragma unroll
    for (int mi = 0; mi < 4; mi++)
        #pragma unroll
        for (int r = 0; r < 4; r++) {
            long row = m0 + wm + mi*16 + lg*4 + r;
            #pragma unroll
            for (int ni = 0; ni < 4; ni++) {
                int col = n0 + wn + ni*16 + lr;
                C[row*VOCAB + col] = acc[mi][ni][r] * INV_S;
            }
        }
}

// ---------------- small kernels ----------------
__global__ __launch_bounds__(256) void embed_kernel(const int* __restrict__ tok,
    const float* __restrict__ emb, float* __restrict__ h)
{
    int n = blockIdx.x;
    int c = threadIdx.x << 2;
    long t = tok[n];
    *(f32x4*)(h + (long)n*D_MODEL + c) = *(const f32x4*)(emb + t*D_MODEL + c);
}

__global__ __launch_bounds__(256) void ropetab_kernel(float* __restrict__ tab)
{
    int idx = blockIdx.x * 256 + threadIdx.x;
    if (idx >= SEQ * 32) return;
    int t = idx >> 5, i = idx & 31;
    double inv = pow(10000.0, -(double)(2*i) / 64.0);
    double ang = (double)t * inv;
    tab[idx*2]   = (float)cos(ang);
    tab[idx*2+1] = (float)sin(ang);
}

__global__ __launch_bounds__(256) void rope_kernel(float* __restrict__ q, float* __restrict__ kk,
    const float* __restrict__ tab)
{
    int gid = blockIdx.x * 256 + threadIdx.x;
    if (gid >= NTOK * 512) return;
    int n   = gid >> 9;
    int rem = gid & 511;
    int hh  = rem >> 5;
    int i   = rem & 31;
    int t   = n & (SEQ - 1);
    float cs = tab[(t*32 + i)*2];
    float sn = tab[(t*32 + i)*2 + 1];
    long base = (long)n * D_MODEL + hh*64 + 2*i;
    float qr = q[base], qi = q[base+1];
    q[base]   = qr*cs - qi*sn;
    q[base+1] = qr*sn + qi*cs;
    float kr = kk[base], ki = kk[base+1];
    kk[base]   = kr*cs - ki*sn;
    kk[base+1] = kr*sn + ki*cs;
}

__global__ __launch_bounds__(64) void gate_kernel(const unsigned short* __restrict__ xf2,
    const float* __restrict__ gw, int* __restrict__ counts,
    int* __restrict__ eid, float* __restrict__ wts, float* __restrict__ pbuf)
{
    int n = blockIdx.x;
    int lane = threadIdx.x;
    float acc[8] = {0,0,0,0,0,0,0,0};
    for (int d0 = lane*4; d0 < D_MODEL; d0 += 256) {
        long idx = (long)n*D_MODEL + d0;
        u16x4 xh = *(const u16x4*)(xf2 + 0*PSA + idx);
        u16x4 xm = *(const u16x4*)(xf2 + 1*PSA + idx);
        #pragma unroll
        for (int j = 0; j < 4; j++) {
            float xv = h2f(xh[j])*INV_S + h2f(xm[j])*INV_M;
            const float* g = gw + (d0+j) * 8;
            #pragma unroll
            for (int e = 0; e < 8; e++) acc[e] += xv * g[e];
        }
    }
    #pragma unroll
    for (int e = 0; e < 8; e++) {
        #pragma unroll
        for (int dd = 32; dd; dd >>= 1) acc[e] += __shfl_xor(acc[e], dd);
    }
    if (lane == 0) {
        float mx = acc[0];
        #pragma unroll
        for (int e = 1; e < 8; e++) mx = fmaxf(mx, acc[e]);
        float pe[8], ssum = 0.f;
        #pragma unroll
        for (int e = 0; e < 8; e++) { pe[e] = expf(acc[e] - mx); ssum += pe[e]; }
        float sinv = 1.f / ssum;
        #pragma unroll
        for (int e = 0; e < 8; e++) { pe[e] *= sinv; pbuf[n*8 + e] = pe[e]; }
        int e1 = 0;
        #pragma unroll
        for (int e = 1; e < 8; e++) if (pe[e] > pe[e1]) e1 = e;
        int e2 = -1;
        #pragma unroll
        for (int e = 0; e < 8; e++) if (e != e1 && (e2 < 0 || pe[e] > pe[e2])) e2 = e;
        float v1 = pe[e1], v2 = pe[e2];
        float wsum = v1 + v2 + 1e-8f;
        eid[n*2] = e1; eid[n*2+1] = e2;
        wts[n*2] = v1 / wsum; wts[n*2+1] = v2 / wsum;
        atomicAdd(counts + e1, 1);
        atomicAdd(counts + e2, 1);
    }
}

__global__ __launch_bounds__(64) void scan_kernel(const int* __restrict__ counts,
    int* __restrict__ offs, int* __restrict__ cursor,
    const float* __restrict__ pbuf, float* __restrict__ aux)
{
    int t = threadIdx.x;
    int e = t & 7, c = t >> 3;
    float s = 0.f;
    for (int n = 0; n < NTOK/8; n++)
        s += pbuf[(c*(NTOK/8) + n)*8 + e];
    #pragma unroll
    for (int dd = 8; dd < 64; dd <<= 1) s += __shfl_xor(s, dd);
    __shared__ float red[8];
    if (t < 8) red[t] = s;
    __syncthreads();
    if (t == 0) {
        int o = 0; float a = 0.f;
        for (int kk = 0; kk < 8; kk++) {
            offs[kk] = o; cursor[kk] = o; o += counts[kk];
            a += (float)counts[kk] * red[kk];
        }
        aux[0] += 8.f * a / ((float)NTOK * (float)NTOK);
    }
}

__global__ __launch_bounds__(256) void assign_kernel(const int* __restrict__ eid,
    const float* __restrict__ wts, int* __restrict__ cursor,
    int* __restrict__ rowidx, float* __restrict__ wrow)
{
    int n = blockIdx.x * 256 + threadIdx.x;
    if (n >= NTOK) return;
    #pragma unroll
    for (int s = 0; s < 2; s++) {
        int e = eid[n*2 + s];
        int p = atomicAdd(cursor + e, 1);
        rowidx[p] = n;
        wrow[p] = wts[n*2 + s];
    }
}

__global__ void write_aux_kernel(float* __restrict__ out, const float* __restrict__ aux)
{
    if (threadIdx.x == 0 && blockIdx.x == 0)
        out[(long)NTOK * VOCAB] = aux[0];
}

// ---------------- launch ----------------
extern "C" void kernel_launch(void* const* d_in, const int* in_sizes, int n_in,
                              void* d_out, int out_size, void* d_ws, size_t ws_size,
                              hipStream_t stream)
{
    const int*   tokens = (const int*)d_in[0];
    const float* emb    = (const float*)d_in[1];
    const float* anw    = (const float*)d_in[2];
    const float* wq     = (const float*)d_in[3];
    const float* wk     = (const float*)d_in[4];
    const float* wv     = (const float*)d_in[5];
    const float* wo     = (const float*)d_in[6];
    const float* fnw    = (const float*)d_in[7];
    const float* gw     = (const float*)d_in[8];
    const float* w1     = (const float*)d_in[9];
    const float* w2     = (const float*)d_in[10];
    const float* w3     = (const float*)d_in[11];
    const float* finw   = (const float*)d_in[12];
    float* out = (float*)d_out;

    char* W = (char*)d_ws;
    const size_t MB = 1024u * 1024u;
    // ctrl block [0, 1MB)
    int*   counts = (int*)(W + 0);
    int*   offs   = (int*)(W + 64);
    int*   cursor = (int*)(W + 128);
    float* aux    = (float*)(W + 192);
    int*   eid    = (int*)(W + 4096);
    float* wts    = (float*)(W + 4096 + 16384);
    int*   rowix  = (int*)(W + 4096 + 32768);
    float* wrow   = (float*)(W + 4096 + 49152);
    float* pbuf   = (float*)(W + 4096 + 65536);
    float* rtab   = (float*)(W + 4096 + 131072 + 65536);
    // big buffers — lifetimes:
    //   wq2/wk2/wv2 [41,53) live wsplitT -> qkv
    //   att [41,49) live attn -> wo (weight planes dead)
    //   g [17,49) MoE phase (qf/kf/vf/att dead)
    // peak 53 MB
    float*          h    = (float*)(W + 1*MB);                   // [1,9)
    unsigned short* hn2  = (unsigned short*)(W + 9*MB);          // [9,17): 2 planes x 4MB
    float*          qf   = (float*)(W + 17*MB);                  // [17,25)
    float*          kf   = (float*)(W + 25*MB);                  // [25,33)
    float*          vf   = (float*)(W + 33*MB);                  // [33,41)
    unsigned short* wq2  = (unsigned short*)(W + 41*MB);         // [41,45)
    unsigned short* wk2  = (unsigned short*)(W + 45*MB);         // [45,49)
    unsigned short* wv2  = (unsigned short*)(W + 49*MB);         // [49,53)
    float*          att  = (float*)(W + 41*MB);                  // [41,49)
    float*          g    = (float*)(W + 17*MB);                  // [17,49) MoE phase

    hipMemsetAsync(W, 0, 256, stream);
    ropetab_kernel<<<(SEQ*32 + 255)/256, 256, 0, stream>>>(rtab);
    embed_kernel<<<NTOK, 256, 0, stream>>>(tokens, emb, h);

    for (int l = 0; l < 2; l++) {
        const float* wql = wq + (size_t)l*D_MODEL*D_MODEL;
        const float* wkl = wk + (size_t)l*D_MODEL*D_MODEL;
        const float* wvl = wv + (size_t)l*D_MODEL*D_MODEL;
        const float* wol = wo + (size_t)l*D_MODEL*D_MODEL;

        rmsnorm_kernel<<<NTOK, 256, 0, stream>>>(h, anw + (size_t)l*D_MODEL, hn2);
        wsplitT_kernel<<<dim3(16, 16, 3), 256, 0, stream>>>(wql, wkl, wvl, wq2, wk2, wv2);
        qkv_kernel<<<dim3(D_MODEL/64, NTOK/64, 3), 256, 0, stream>>>(hn2, wq2, wk2, wv2, qf, kf, vf);
        rope_kernel<<<(NTOK*512 + 255)/256, 256, 0, stream>>>(qf, kf, rtab);
        attn_kernel<<<dim3(SEQ/64, BATCH*NHEADS), 256, 0, stream>>>(qf, kf, vf, att);
        wo_kernel<<<dim3(D_MODEL/64, NTOK/64), 256, 0, stream>>>(att, wol, h);

        rmsnorm_kernel<<<NTOK, 256, 0, stream>>>(h, fnw + (size_t)l*D_MODEL, hn2);
        hipMemsetAsync(W, 0, 160, stream);   // counts/offs/cursor (aux preserved @192)
        gate_kernel<<<NTOK, 64, 0, stream>>>(hn2, gw + (size_t)l*D_MODEL*NEXP, counts, eid, wts, pbuf);
        scan_kernel<<<1, 64, 0, stream>>>(counts, offs, cursor, pbuf, aux);
        assign_kernel<<<(NTOK + 255)/256, 256, 0, stream>>>(eid, wts, cursor, rowix, wrow);

        const float* w1l = w1 + (size_t)l*NEXP*D_MODEL*FFH;
        const float* w3l = w3 + (size_t)l*NEXP*D_MODEL*FFH;
        const float* w2l = w2 + (size_t)l*NEXP*FFH*D_MODEL;
        dim3 g13(FFH/128, 2*NTOK/64, NEXP);
        dim3 g2d(D_MODEL/64, 2*NTOK/64, NEXP);
        if (l == 0) {
            moe13_kernel<2><<<g13, 256, 0, stream>>>(hn2, w1l, w3l, g, rowix, counts, offs);
            w2_kernel<2><<<g2d, 256, 0, stream>>>(g, w2l, h, rowix, wrow, counts, offs);
        } else {
            moe13_kernel<1><<<g13, 256, 0, stream>>>(hn2, w1l, w3l, g, rowix, counts, offs);
            w2_kernel<1><<<g2d, 256, 0, stream>>>(g, w2l, h, rowix, wrow, counts, offs);
        }
    }

    rmsnorm_kernel<<<NTOK, 256, 0, stream>>>(h, finw, hn2);
    logits_kernel<<<dim3(NTOK/128, VOCAB/128), 256, 0, stream>>>(hn2, emb, out);
    write_aux_kernel<<<1, 1, 0, stream>>>(out, aux);
}